// Round 2
// baseline (2341.967 us; speedup 1.0000x reference)
//
#include <hip/hip_runtime.h>
#include <hip/hip_bf16.h>
#include <cstdint>
#include <cstddef>

// ---------------------------------------------------------------------------
// Tiled fp32 GEMM: out[nrows x 64] = act(Z[nrows x K] @ W[K x 64] + bias)
// ACT: 0=none, 1=relu, 2=tanh. Block 256 threads -> 64x64 tile, 4x4 per thread.
// ---------------------------------------------------------------------------
template <int ACT>
__global__ __launch_bounds__(256) void gemm64(const float* __restrict__ Z,
                                              const float* __restrict__ W,
                                              const float* __restrict__ bias,
                                              float* __restrict__ out,
                                              int nrows, int K) {
    __shared__ float zt[64][65];
    __shared__ float wt[64][65];
    const int row0 = blockIdx.x * 64;
    const int tx = threadIdx.x & 15;   // 16 col groups
    const int ty = threadIdx.x >> 4;   // 16 row groups
    float acc[4][4] = {};

    for (int kb = 0; kb < K; kb += 64) {
#pragma unroll
        for (int i = 0; i < 16; ++i) {
            int idx = threadIdx.x + 256 * i;  // 0..4095
            int r = idx >> 6, c = idx & 63;
            int gr = row0 + r;
            zt[r][c] = (gr < nrows) ? Z[(size_t)gr * K + kb + c] : 0.f;
            wt[r][c] = W[(size_t)(kb + r) * 64 + c];
        }
        __syncthreads();
#pragma unroll
        for (int kk = 0; kk < 64; ++kk) {
            float a[4], b[4];
#pragma unroll
            for (int i = 0; i < 4; ++i) a[i] = zt[ty * 4 + i][kk];
#pragma unroll
            for (int j = 0; j < 4; ++j) b[j] = wt[kk][tx * 4 + j];
#pragma unroll
            for (int i = 0; i < 4; ++i)
#pragma unroll
                for (int j = 0; j < 4; ++j) acc[i][j] += a[i] * b[j];
        }
        __syncthreads();
    }

#pragma unroll
    for (int i = 0; i < 4; ++i) {
        int gr = row0 + ty * 4 + i;
        if (gr >= nrows) continue;
#pragma unroll
        for (int j = 0; j < 4; ++j) {
            float v = acc[i][j] + bias[tx * 4 + j];
            if (ACT == 1) v = fmaxf(v, 0.f);
            if (ACT == 2) v = tanhf(v);
            out[(size_t)gr * 64 + tx * 4 + j] = v;
        }
    }
}

// ---------------------------------------------------------------------------
// Attention scalars: s[n][2k]   = h[n] . att_w[l][k][0:64]
//                    s[n][2k+1] = h[n] . att_w[l][k][64:128]
// One wave per node.
// ---------------------------------------------------------------------------
__global__ __launch_bounds__(256) void s_kernel(const float* __restrict__ h,
                                                const float* __restrict__ att_w_l,
                                                float* __restrict__ s, int nnodes) {
    int wid = (int)((blockIdx.x * (size_t)blockDim.x + threadIdx.x) >> 6);
    int lane = threadIdx.x & 63;
    if (wid >= nnodes) return;
    float hv = h[(size_t)wid * 64 + lane];
#pragma unroll
    for (int k = 0; k < 4; ++k) {
        float plo = hv * att_w_l[k * 128 + lane];
        float phi = hv * att_w_l[k * 128 + 64 + lane];
#pragma unroll
        for (int off = 32; off >= 1; off >>= 1) {
            plo += __shfl_xor(plo, off);
            phi += __shfl_xor(phi, off);
        }
        if (lane == 0) {
            s[(size_t)wid * 8 + 2 * k] = plo;
            s[(size_t)wid * 8 + 2 * k + 1] = phi;
        }
    }
}

// ---------------------------------------------------------------------------
// Edge scatter (both directions of one edge list): one wave per edge.
//   dir A (k0): src=r, dst=c : outs[r][64*k0 + j] += h[c][j] * score_a
//   dir B (k1): src=c, dst=r : outs[c][64*k1 + j] += h[r][j] * score_b
// score = exp(tanh(s1[src] + s2[dst] + att_b[k]))
// ---------------------------------------------------------------------------
__global__ __launch_bounds__(256) void scatter_kernel(const float* __restrict__ h,
                                                      const float* __restrict__ s,
                                                      const int* __restrict__ eidx,
                                                      const float* __restrict__ att_b_l,
                                                      float* __restrict__ outs,
                                                      int nedges, int k0) {
    int wid = (int)((blockIdx.x * (size_t)blockDim.x + threadIdx.x) >> 6);
    int lane = threadIdx.x & 63;
    if (wid >= nedges) return;
    int r = eidx[wid];
    int c = eidx[nedges + wid];
    int k1 = k0 + 1;
    float sv = 0.f;
    if (lane < 2) {
        int src = lane ? c : r;
        int dst = lane ? r : c;
        int k = lane ? k1 : k0;
        float t = s[(size_t)src * 8 + 2 * k] + s[(size_t)dst * 8 + 2 * k + 1] + att_b_l[k];
        sv = expf(tanhf(t));
    }
    float sa = __shfl(sv, 0);
    float sb = __shfl(sv, 1);
    float hc = h[(size_t)c * 64 + lane];
    float hr = h[(size_t)r * 64 + lane];
    atomicAdd(&outs[(size_t)r * 256 + k0 * 64 + lane], hc * sa);
    atomicAdd(&outs[(size_t)c * 256 + k1 * 64 + lane], hr * sb);
}

// ---------------------------------------------------------------------------
// Head gather: x12[b] = [zc[idx1[b]], zc[idx2[b]]], x21[b] = swapped.
// zc[n] = [emb0[n] (64), emb1[n] (64)]. One block (256 thr) per b.
// ---------------------------------------------------------------------------
__global__ __launch_bounds__(256) void gather_heads(const float* __restrict__ emb0,
                                                    const float* __restrict__ emb1,
                                                    const int* __restrict__ idx1,
                                                    const int* __restrict__ idx2,
                                                    float* __restrict__ x12,
                                                    float* __restrict__ x21, int B) {
    int b = blockIdx.x;
    int j = threadIdx.x;
    int i1 = idx1[b], i2 = idx2[b];
    int seg = j >> 6, o = j & 63;
    const float* e = (seg & 1) ? emb1 : emb0;
    int n12 = (seg < 2) ? i1 : i2;
    int n21 = (seg < 2) ? i2 : i1;
    x12[(size_t)b * 256 + j] = e[(size_t)n12 * 64 + o];
    x21[(size_t)b * 256 + j] = e[(size_t)n21 * 64 + o];
}

// ---------------------------------------------------------------------------
// Final tiny GEMM: out[nrows x 2] = Z[nrows x 64] @ W[64 x 2] + bias
// ---------------------------------------------------------------------------
__global__ __launch_bounds__(256) void gemm_m2(const float* __restrict__ Z,
                                               const float* __restrict__ W,
                                               const float* __restrict__ bias,
                                               float* __restrict__ out, int nrows) {
    int row = blockIdx.x * blockDim.x + threadIdx.x;
    if (row >= nrows) return;
    float acc0 = bias[0], acc1 = bias[1];
#pragma unroll
    for (int kk = 0; kk < 64; ++kk) {
        float v = Z[(size_t)row * 64 + kk];
        acc0 += v * W[kk * 2 + 0];
        acc1 += v * W[kk * 2 + 1];
    }
    out[(size_t)row * 2 + 0] = acc0;
    out[(size_t)row * 2 + 1] = acc1;
}

static inline int cdiv(int a, int b) { return (a + b - 1) / b; }

extern "C" void kernel_launch(void* const* d_in, const int* in_sizes, int n_in,
                              void* d_out, int out_size, void* d_ws, size_t ws_size,
                              hipStream_t stream) {
    const float* x       = (const float*)d_in[0];
    const int* edge_pos  = (const int*)d_in[1];
    const int* edge_neg  = (const int*)d_in[2];
    const int* idx1      = (const int*)d_in[3];
    const int* idx2      = (const int*)d_in[4];
    const float* lin_w0  = (const float*)d_in[5];
    const float* lin_b0  = (const float*)d_in[6];
    const float* lin_w1  = (const float*)d_in[7];
    const float* lin_b1  = (const float*)d_in[8];
    const float* att_w   = (const float*)d_in[9];   // (2,4,128)
    const float* att_b   = (const float*)d_in[10];  // (2,4)
    const float* cat_w   = (const float*)d_in[11];  // (2,256,64)
    const float* cat_b   = (const float*)d_in[12];  // (2,64)
    const float* sw1 = (const float*)d_in[13];
    const float* sb1 = (const float*)d_in[14];
    const float* sw2 = (const float*)d_in[15];
    const float* sb2 = (const float*)d_in[16];
    const float* sw3 = (const float*)d_in[17];
    const float* sb3 = (const float*)d_in[18];
    const float* sw4 = (const float*)d_in[19];
    const float* sb4 = (const float*)d_in[20];
    const float* dw1 = (const float*)d_in[21];
    const float* db1 = (const float*)d_in[22];
    const float* dw2 = (const float*)d_in[23];
    const float* db2 = (const float*)d_in[24];
    float* out = (float*)d_out;

    const int N = in_sizes[0] / 64;  // 100000
    const int E = in_sizes[1] / 2;   // 800000
    const int B = in_sizes[3];       // 4096

    // -------- workspace layout (floats) --------
    float* ws = (float*)d_ws;
    float* h    = ws;                          // N*64
    float* outs = h + (size_t)N * 64;          // N*256
    float* sbuf = outs + (size_t)N * 256;      // N*8
    float* emb0 = sbuf + (size_t)N * 8;        // N*64
    float* emb1 = emb0 + (size_t)N * 64;       // N*64
    // heads overlay the (now dead) h slot after the GNN layers:
    float* x12 = ws;                     // B*256
    float* x21 = x12 + (size_t)B * 256;  // B*256
    float* hsA = x21 + (size_t)B * 256;  // B*64
    float* hsB = hsA + (size_t)B * 64;   // B*64

    const int gemm_blocks_N = cdiv(N, 64);
    const int gemm_blocks_B = cdiv(B, 64);
    const int s_blocks = cdiv(N, 4);        // 4 waves / block
    const int scat_blocks = cdiv(E, 4);     // 4 edges / block

    for (int l = 0; l < 2; ++l) {
        const float* zin = (l == 0) ? x : emb0;
        const float* lw = (l == 0) ? lin_w0 : lin_w1;
        const float* lb = (l == 0) ? lin_b0 : lin_b1;
        // h = zin @ lw + lb
        gemm64<0><<<gemm_blocks_N, 256, 0, stream>>>(zin, lw, lb, h, N, 64);
        // attention scalars
        s_kernel<<<s_blocks, 256, 0, stream>>>(h, att_w + (size_t)l * 512, sbuf, N);
        // zero accumulators
        hipMemsetAsync(outs, 0, (size_t)N * 256 * sizeof(float), stream);
        // scatter both edge lists
        scatter_kernel<<<scat_blocks, 256, 0, stream>>>(h, sbuf, edge_pos,
                                                        att_b + (size_t)l * 4, outs, E, 0);
        scatter_kernel<<<scat_blocks, 256, 0, stream>>>(h, sbuf, edge_neg,
                                                        att_b + (size_t)l * 4, outs, E, 2);
        // z_next = tanh(outs @ cat_w[l] + cat_b[l])
        float* embl = (l == 0) ? emb0 : emb1;
        gemm64<2><<<gemm_blocks_N, 256, 0, stream>>>(outs, cat_w + (size_t)l * 16384,
                                                     cat_b + (size_t)l * 64, embl, N, 256);
    }

    // -------- heads --------
    gather_heads<<<B, 256, 0, stream>>>(emb0, emb1, idx1, idx2, x12, x21, B);

    // sign head: relu chain then M=2
    gemm64<1><<<gemm_blocks_B, 256, 0, stream>>>(x12, sw1, sb1, hsA, B, 256);
    gemm64<1><<<gemm_blocks_B, 256, 0, stream>>>(hsA, sw2, sb2, hsB, B, 64);
    gemm64<1><<<gemm_blocks_B, 256, 0, stream>>>(hsB, sw3, sb3, hsA, B, 64);
    gemm_m2<<<cdiv(B, 256), 256, 0, stream>>>(hsA, sw4, sb4, out, B);

    // direct head: x12 then x21
    gemm64<1><<<gemm_blocks_B, 256, 0, stream>>>(x12, dw1, db1, hsB, B, 256);
    gemm_m2<<<cdiv(B, 256), 256, 0, stream>>>(hsB, dw2, db2, out + (size_t)B * 2, B);
    gemm64<1><<<gemm_blocks_B, 256, 0, stream>>>(x21, dw1, db1, hsB, B, 256);
    gemm_m2<<<cdiv(B, 256), 256, 0, stream>>>(hsB, dw2, db2, out + (size_t)B * 4, B);
}

// Round 3
// 2321.068 us; speedup vs baseline: 1.0090x; 1.0090x over previous
//
#include <hip/hip_runtime.h>
#include <hip/hip_bf16.h>
#include <cstdint>
#include <cstddef>

// ---------------------------------------------------------------------------
// Tiled fp32 GEMM: out[nrows x 64] = act(Z[nrows x K] @ W[K x 64] + bias)
// ACT: 0=none, 1=relu, 2=tanh. Block 256 threads -> 64x64 tile, 4x4 per thread.
// ---------------------------------------------------------------------------
template <int ACT>
__global__ __launch_bounds__(256) void gemm64(const float* __restrict__ Z,
                                              const float* __restrict__ W,
                                              const float* __restrict__ bias,
                                              float* __restrict__ out,
                                              int nrows, int K) {
    __shared__ float zt[64][65];
    __shared__ float wt[64][65];
    const int row0 = blockIdx.x * 64;
    const int tx = threadIdx.x & 15;   // 16 col groups
    const int ty = threadIdx.x >> 4;   // 16 row groups
    float acc[4][4] = {};

    for (int kb = 0; kb < K; kb += 64) {
#pragma unroll
        for (int i = 0; i < 16; ++i) {
            int idx = threadIdx.x + 256 * i;  // 0..4095
            int r = idx >> 6, c = idx & 63;
            int gr = row0 + r;
            zt[r][c] = (gr < nrows) ? Z[(size_t)gr * K + kb + c] : 0.f;
            wt[r][c] = W[(size_t)(kb + r) * 64 + c];
        }
        __syncthreads();
#pragma unroll
        for (int kk = 0; kk < 64; ++kk) {
            float a[4], b[4];
#pragma unroll
            for (int i = 0; i < 4; ++i) a[i] = zt[ty * 4 + i][kk];
#pragma unroll
            for (int j = 0; j < 4; ++j) b[j] = wt[kk][tx * 4 + j];
#pragma unroll
            for (int i = 0; i < 4; ++i)
#pragma unroll
                for (int j = 0; j < 4; ++j) acc[i][j] += a[i] * b[j];
        }
        __syncthreads();
    }

#pragma unroll
    for (int i = 0; i < 4; ++i) {
        int gr = row0 + ty * 4 + i;
        if (gr >= nrows) continue;
#pragma unroll
        for (int j = 0; j < 4; ++j) {
            float v = acc[i][j] + bias[tx * 4 + j];
            if (ACT == 1) v = fmaxf(v, 0.f);
            if (ACT == 2) v = tanhf(v);
            out[(size_t)gr * 64 + tx * 4 + j] = v;
        }
    }
}

// ---------------------------------------------------------------------------
// Attention scalars: s[n][2k]   = h[n] . att_w[l][k][0:64]
//                    s[n][2k+1] = h[n] . att_w[l][k][64:128]
// One wave per node.
// ---------------------------------------------------------------------------
__global__ __launch_bounds__(256) void s_kernel(const float* __restrict__ h,
                                                const float* __restrict__ att_w_l,
                                                float* __restrict__ s, int nnodes) {
    int wid = (int)((blockIdx.x * (size_t)blockDim.x + threadIdx.x) >> 6);
    int lane = threadIdx.x & 63;
    if (wid >= nnodes) return;
    float hv = h[(size_t)wid * 64 + lane];
#pragma unroll
    for (int k = 0; k < 4; ++k) {
        float plo = hv * att_w_l[k * 128 + lane];
        float phi = hv * att_w_l[k * 128 + 64 + lane];
#pragma unroll
        for (int off = 32; off >= 1; off >>= 1) {
            plo += __shfl_xor(plo, off);
            phi += __shfl_xor(phi, off);
        }
        if (lane == 0) {
            s[(size_t)wid * 8 + 2 * k] = plo;
            s[(size_t)wid * 8 + 2 * k + 1] = phi;
        }
    }
}

// ---------------------------------------------------------------------------
// CSR build: 4 directed graphs over N nodes, 4E entries total.
//   k=0: pos src=r (dst=c), k=1: pos src=c (dst=r),
//   k=2: neg src=r (dst=c), k=3: neg src=c (dst=r)
// cnt/off flattened k-major: slot(k,n) = k*N + n.
// ---------------------------------------------------------------------------
__global__ __launch_bounds__(256) void count_kernel(const int* __restrict__ ep,
                                                    const int* __restrict__ en,
                                                    int* __restrict__ cnt,
                                                    int N, int E) {
    int i = blockIdx.x * blockDim.x + threadIdx.x;
    if (i < E) {
        int r = ep[i], c = ep[E + i];
        atomicAdd(&cnt[0 * N + r], 1);
        atomicAdd(&cnt[1 * N + c], 1);
    } else if (i < 2 * E) {
        int j = i - E;
        int r = en[j], c = en[E + j];
        atomicAdd(&cnt[2 * N + r], 1);
        atomicAdd(&cnt[3 * N + c], 1);
    }
}

// Exclusive scan, 3-kernel hierarchy. 256 thr x 8 elem = 2048/block.
__global__ __launch_bounds__(256) void scan1(const int* __restrict__ in,
                                             int* __restrict__ out,
                                             int* __restrict__ part, int M) {
    __shared__ int ts[256];
    int base = blockIdx.x * 2048 + threadIdx.x * 8;
    int v[8];
    int run = 0;
#pragma unroll
    for (int t = 0; t < 8; ++t) {
        int x = (base + t < M) ? in[base + t] : 0;
        v[t] = run;
        run += x;
    }
    ts[threadIdx.x] = run;
    __syncthreads();
    for (int off = 1; off < 256; off <<= 1) {
        int t = (threadIdx.x >= off) ? ts[threadIdx.x - off] : 0;
        __syncthreads();
        ts[threadIdx.x] += t;
        __syncthreads();
    }
    int texcl = ts[threadIdx.x] - run;
    if (part && threadIdx.x == 255) part[blockIdx.x] = ts[255];
#pragma unroll
    for (int t = 0; t < 8; ++t)
        if (base + t < M) out[base + t] = v[t] + texcl;
}

// add block offsets; also duplicate into cursor array and set sentinel
__global__ __launch_bounds__(256) void scan3(int* __restrict__ off,
                                             int* __restrict__ cur,
                                             const int* __restrict__ part,
                                             int M, int total) {
    int base = blockIdx.x * 2048 + threadIdx.x * 8;
    int p = part[blockIdx.x];
#pragma unroll
    for (int t = 0; t < 8; ++t) {
        int i = base + t;
        if (i < M) {
            int v = off[i] + p;
            off[i] = v;
            cur[i] = v;
        }
    }
    if (blockIdx.x == 0 && threadIdx.x == 0) off[M] = total;
}

__global__ __launch_bounds__(256) void fill_kernel(const int* __restrict__ ep,
                                                   const int* __restrict__ en,
                                                   int* __restrict__ cur,
                                                   int* __restrict__ ent,
                                                   int N, int E) {
    int i = blockIdx.x * blockDim.x + threadIdx.x;
    if (i < E) {
        int r = ep[i], c = ep[E + i];
        ent[atomicAdd(&cur[0 * N + r], 1)] = c;
        ent[atomicAdd(&cur[1 * N + c], 1)] = r;
    } else if (i < 2 * E) {
        int j = i - E;
        int r = en[j], c = en[E + j];
        ent[atomicAdd(&cur[2 * N + r], 1)] = c;
        ent[atomicAdd(&cur[3 * N + c], 1)] = r;
    }
}

// ---------------------------------------------------------------------------
// CSR aggregate: one wave per (node n, slot k). Replaces memset + scatter.
//   outs[n][64k + lane] = sum_{j in seg(k,n)} h[ent[j]][lane] * score
//   score = exp(tanh(s[n][2k] + s[dst][2k+1] + att_b[k]))
// ---------------------------------------------------------------------------
__global__ __launch_bounds__(256) void aggregate(const float* __restrict__ h,
                                                 const float* __restrict__ s,
                                                 const int* __restrict__ off,
                                                 const int* __restrict__ ent,
                                                 const float* __restrict__ att_b_l,
                                                 float* __restrict__ outs, int N) {
    int n = blockIdx.x;
    int k = threadIdx.x >> 6;
    int lane = threadIdx.x & 63;
    int beg = off[k * N + n];
    int end = off[k * N + n + 1];
    float s1 = s[(size_t)n * 8 + 2 * k] + att_b_l[k];
    float acc = 0.f;
    for (int j = beg; j < end; ++j) {
        int dst = ent[j];
        float sc = expf(tanhf(s1 + s[(size_t)dst * 8 + 2 * k + 1]));
        acc += h[(size_t)dst * 64 + lane] * sc;
    }
    outs[(size_t)n * 256 + k * 64 + lane] = acc;
}

// ---------------------------------------------------------------------------
// Head gather: x12[b] = [zc[idx1[b]], zc[idx2[b]]], x21[b] = swapped.
// ---------------------------------------------------------------------------
__global__ __launch_bounds__(256) void gather_heads(const float* __restrict__ emb0,
                                                    const float* __restrict__ emb1,
                                                    const int* __restrict__ idx1,
                                                    const int* __restrict__ idx2,
                                                    float* __restrict__ x12,
                                                    float* __restrict__ x21, int B) {
    int b = blockIdx.x;
    int j = threadIdx.x;
    int i1 = idx1[b], i2 = idx2[b];
    int seg = j >> 6, o = j & 63;
    const float* e = (seg & 1) ? emb1 : emb0;
    int n12 = (seg < 2) ? i1 : i2;
    int n21 = (seg < 2) ? i2 : i1;
    x12[(size_t)b * 256 + j] = e[(size_t)n12 * 64 + o];
    x21[(size_t)b * 256 + j] = e[(size_t)n21 * 64 + o];
}

// ---------------------------------------------------------------------------
// Final tiny GEMM: out[nrows x 2] = Z[nrows x 64] @ W[64 x 2] + bias
// ---------------------------------------------------------------------------
__global__ __launch_bounds__(256) void gemm_m2(const float* __restrict__ Z,
                                               const float* __restrict__ W,
                                               const float* __restrict__ bias,
                                               float* __restrict__ out, int nrows) {
    int row = blockIdx.x * blockDim.x + threadIdx.x;
    if (row >= nrows) return;
    float acc0 = bias[0], acc1 = bias[1];
#pragma unroll
    for (int kk = 0; kk < 64; ++kk) {
        float v = Z[(size_t)row * 64 + kk];
        acc0 += v * W[kk * 2 + 0];
        acc1 += v * W[kk * 2 + 1];
    }
    out[(size_t)row * 2 + 0] = acc0;
    out[(size_t)row * 2 + 1] = acc1;
}

static inline int cdiv(int a, int b) { return (a + b - 1) / b; }

extern "C" void kernel_launch(void* const* d_in, const int* in_sizes, int n_in,
                              void* d_out, int out_size, void* d_ws, size_t ws_size,
                              hipStream_t stream) {
    const float* x       = (const float*)d_in[0];
    const int* edge_pos  = (const int*)d_in[1];
    const int* edge_neg  = (const int*)d_in[2];
    const int* idx1      = (const int*)d_in[3];
    const int* idx2      = (const int*)d_in[4];
    const float* lin_w0  = (const float*)d_in[5];
    const float* lin_b0  = (const float*)d_in[6];
    const float* lin_w1  = (const float*)d_in[7];
    const float* lin_b1  = (const float*)d_in[8];
    const float* att_w   = (const float*)d_in[9];   // (2,4,128)
    const float* att_b   = (const float*)d_in[10];  // (2,4)
    const float* cat_w   = (const float*)d_in[11];  // (2,256,64)
    const float* cat_b   = (const float*)d_in[12];  // (2,64)
    const float* sw1 = (const float*)d_in[13];
    const float* sb1 = (const float*)d_in[14];
    const float* sw2 = (const float*)d_in[15];
    const float* sb2 = (const float*)d_in[16];
    const float* sw3 = (const float*)d_in[17];
    const float* sb3 = (const float*)d_in[18];
    const float* sw4 = (const float*)d_in[19];
    const float* sb4 = (const float*)d_in[20];
    const float* dw1 = (const float*)d_in[21];
    const float* db1 = (const float*)d_in[22];
    const float* dw2 = (const float*)d_in[23];
    const float* db2 = (const float*)d_in[24];
    float* out = (float*)d_out;

    const int N = in_sizes[0] / 64;  // 100000
    const int E = in_sizes[1] / 2;   // 800000
    const int B = in_sizes[3];       // 4096

    // -------- workspace layout --------
    float* ws = (float*)d_ws;
    float* h    = ws;                          // N*64
    float* outs = h + (size_t)N * 64;          // N*256
    float* sbuf = outs + (size_t)N * 256;      // N*8
    float* emb0 = sbuf + (size_t)N * 8;        // N*64
    float* emb1 = emb0 + (size_t)N * 64;       // N*64 (CSR overlays this until written)

    // CSR overlay inside emb1 region (dead until final cat-GEMM):
    //   cnt[4N] | off[4N+1] | cur[4N] | ent[4E] | part[256]  == ~4.4M ints < 6.4M floats
    int* cnt  = (int*)emb1;
    int* off  = cnt + (size_t)4 * N;
    int* cur  = off + (size_t)4 * N + 1;
    int* ent  = cur + (size_t)4 * N;
    int* part = ent + (size_t)4 * E;

    // heads overlay the (dead after GNN) h slot:
    float* x12 = ws;                     // B*256
    float* x21 = x12 + (size_t)B * 256;  // B*256
    float* hsA = x21 + (size_t)B * 256;  // B*64
    float* hsB = hsA + (size_t)B * 64;   // B*64

    const int gemm_blocks_N = cdiv(N, 64);
    const int gemm_blocks_B = cdiv(B, 64);
    const int s_blocks = cdiv(N, 4);        // 4 waves / block
    const int eg_blocks = cdiv(2 * E, 256); // count / fill
    const int M4 = 4 * N;
    const int scan_blocks = cdiv(M4, 2048);

    // -------- build CSR (shared by both layers) --------
    hipMemsetAsync(cnt, 0, (size_t)M4 * sizeof(int), stream);
    count_kernel<<<eg_blocks, 256, 0, stream>>>(edge_pos, edge_neg, cnt, N, E);
    scan1<<<scan_blocks, 256, 0, stream>>>(cnt, off, part, M4);
    scan1<<<1, 256, 0, stream>>>(part, part, nullptr, scan_blocks);
    scan3<<<scan_blocks, 256, 0, stream>>>(off, cur, part, M4, 4 * E);
    fill_kernel<<<eg_blocks, 256, 0, stream>>>(edge_pos, edge_neg, cur, ent, N, E);

    // -------- GNN layers --------
    for (int l = 0; l < 2; ++l) {
        const float* zin = (l == 0) ? x : emb0;
        const float* lw = (l == 0) ? lin_w0 : lin_w1;
        const float* lb = (l == 0) ? lin_b0 : lin_b1;
        gemm64<0><<<gemm_blocks_N, 256, 0, stream>>>(zin, lw, lb, h, N, 64);
        s_kernel<<<s_blocks, 256, 0, stream>>>(h, att_w + (size_t)l * 512, sbuf, N);
        aggregate<<<N, 256, 0, stream>>>(h, sbuf, off, ent,
                                         att_b + (size_t)l * 4, outs, N);
        float* embl = (l == 0) ? emb0 : emb1;
        gemm64<2><<<gemm_blocks_N, 256, 0, stream>>>(outs, cat_w + (size_t)l * 16384,
                                                     cat_b + (size_t)l * 64, embl, N, 256);
    }

    // -------- heads --------
    gather_heads<<<B, 256, 0, stream>>>(emb0, emb1, idx1, idx2, x12, x21, B);

    gemm64<1><<<gemm_blocks_B, 256, 0, stream>>>(x12, sw1, sb1, hsA, B, 256);
    gemm64<1><<<gemm_blocks_B, 256, 0, stream>>>(hsA, sw2, sb2, hsB, B, 64);
    gemm64<1><<<gemm_blocks_B, 256, 0, stream>>>(hsB, sw3, sb3, hsA, B, 64);
    gemm_m2<<<cdiv(B, 256), 256, 0, stream>>>(hsA, sw4, sb4, out, B);

    gemm64<1><<<gemm_blocks_B, 256, 0, stream>>>(x12, dw1, db1, hsB, B, 256);
    gemm_m2<<<cdiv(B, 256), 256, 0, stream>>>(hsB, dw2, db2, out + (size_t)B * 2, B);
    gemm64<1><<<gemm_blocks_B, 256, 0, stream>>>(x21, dw1, db1, hsB, B, 256);
    gemm_m2<<<cdiv(B, 256), 256, 0, stream>>>(hsB, dw2, db2, out + (size_t)B * 4, B);
}

// Round 4
// 1858.234 us; speedup vs baseline: 1.2603x; 1.2491x over previous
//
#include <hip/hip_runtime.h>
#include <hip/hip_bf16.h>
#include <hip/hip_fp16.h>
#include <cstdint>
#include <cstddef>

// ---------------------------------------------------------------------------
// Tiled fp32 GEMM: out[nrows x 64] = act(Z[nrows x K] @ W[K x 64] + bias)
// ACT: 0=none, 1=relu, 2=tanh. H16: write __half output instead of float.
// Block 256 threads -> 64x64 tile, 4x4 per thread.
// ---------------------------------------------------------------------------
template <int ACT, bool H16>
__global__ __launch_bounds__(256) void gemm64(const float* __restrict__ Z,
                                              const float* __restrict__ W,
                                              const float* __restrict__ bias,
                                              void* __restrict__ outp,
                                              int nrows, int K) {
    __shared__ float zt[64][65];
    __shared__ float wt[64][65];
    const int row0 = blockIdx.x * 64;
    const int tx = threadIdx.x & 15;   // 16 col groups
    const int ty = threadIdx.x >> 4;   // 16 row groups
    float acc[4][4] = {};

    for (int kb = 0; kb < K; kb += 64) {
#pragma unroll
        for (int i = 0; i < 16; ++i) {
            int idx = threadIdx.x + 256 * i;  // 0..4095
            int r = idx >> 6, c = idx & 63;
            int gr = row0 + r;
            zt[r][c] = (gr < nrows) ? Z[(size_t)gr * K + kb + c] : 0.f;
            wt[r][c] = W[(size_t)(kb + r) * 64 + c];
        }
        __syncthreads();
#pragma unroll
        for (int kk = 0; kk < 64; ++kk) {
            float a[4], b[4];
#pragma unroll
            for (int i = 0; i < 4; ++i) a[i] = zt[ty * 4 + i][kk];
#pragma unroll
            for (int j = 0; j < 4; ++j) b[j] = wt[kk][tx * 4 + j];
#pragma unroll
            for (int i = 0; i < 4; ++i)
#pragma unroll
                for (int j = 0; j < 4; ++j) acc[i][j] += a[i] * b[j];
        }
        __syncthreads();
    }

#pragma unroll
    for (int i = 0; i < 4; ++i) {
        int gr = row0 + ty * 4 + i;
        if (gr >= nrows) continue;
#pragma unroll
        for (int j = 0; j < 4; ++j) {
            float v = acc[i][j] + bias[tx * 4 + j];
            if (ACT == 1) v = fmaxf(v, 0.f);
            if (ACT == 2) v = tanhf(v);
            if (H16)
                ((__half*)outp)[(size_t)gr * 64 + tx * 4 + j] = __float2half_rn(v);
            else
                ((float*)outp)[(size_t)gr * 64 + tx * 4 + j] = v;
        }
    }
}

// ---------------------------------------------------------------------------
// Attention scalars from fp16 h: s[n][2k] = h[n].att_w[k][0:64], etc.
// One wave per node.
// ---------------------------------------------------------------------------
__global__ __launch_bounds__(256) void s_kernel(const __half* __restrict__ h16,
                                                const float* __restrict__ att_w_l,
                                                float* __restrict__ s, int nnodes) {
    int wid = (int)((blockIdx.x * (size_t)blockDim.x + threadIdx.x) >> 6);
    int lane = threadIdx.x & 63;
    if (wid >= nnodes) return;
    float hv = __half2float(h16[(size_t)wid * 64 + lane]);
#pragma unroll
    for (int k = 0; k < 4; ++k) {
        float plo = hv * att_w_l[k * 128 + lane];
        float phi = hv * att_w_l[k * 128 + 64 + lane];
#pragma unroll
        for (int off = 32; off >= 1; off >>= 1) {
            plo += __shfl_xor(plo, off);
            phi += __shfl_xor(phi, off);
        }
        if (lane == 0) {
            s[(size_t)wid * 8 + 2 * k] = plo;
            s[(size_t)wid * 8 + 2 * k + 1] = phi;
        }
    }
}

// ---------------------------------------------------------------------------
// CSR build: 4 directed graphs over N nodes, 4E entries total.
//   k=0: pos src=r (dst=c), k=1: pos src=c (dst=r),
//   k=2: neg src=r (dst=c), k=3: neg src=c (dst=r)
// ---------------------------------------------------------------------------
__global__ __launch_bounds__(256) void count_kernel(const int* __restrict__ ep,
                                                    const int* __restrict__ en,
                                                    int* __restrict__ cnt,
                                                    int N, int E) {
    int i = blockIdx.x * blockDim.x + threadIdx.x;
    if (i < E) {
        int r = ep[i], c = ep[E + i];
        atomicAdd(&cnt[0 * N + r], 1);
        atomicAdd(&cnt[1 * N + c], 1);
    } else if (i < 2 * E) {
        int j = i - E;
        int r = en[j], c = en[E + j];
        atomicAdd(&cnt[2 * N + r], 1);
        atomicAdd(&cnt[3 * N + c], 1);
    }
}

// Exclusive scan, 3-kernel hierarchy. 256 thr x 8 elem = 2048/block.
__global__ __launch_bounds__(256) void scan1(const int* __restrict__ in,
                                             int* __restrict__ out,
                                             int* __restrict__ part, int M) {
    __shared__ int ts[256];
    int base = blockIdx.x * 2048 + threadIdx.x * 8;
    int v[8];
    int run = 0;
#pragma unroll
    for (int t = 0; t < 8; ++t) {
        int x = (base + t < M) ? in[base + t] : 0;
        v[t] = run;
        run += x;
    }
    ts[threadIdx.x] = run;
    __syncthreads();
    for (int off = 1; off < 256; off <<= 1) {
        int t = (threadIdx.x >= off) ? ts[threadIdx.x - off] : 0;
        __syncthreads();
        ts[threadIdx.x] += t;
        __syncthreads();
    }
    int texcl = ts[threadIdx.x] - run;
    if (part && threadIdx.x == 255) part[blockIdx.x] = ts[255];
#pragma unroll
    for (int t = 0; t < 8; ++t)
        if (base + t < M) out[base + t] = v[t] + texcl;
}

// add block offsets; also duplicate into cursor array and set sentinel
__global__ __launch_bounds__(256) void scan3(int* __restrict__ off,
                                             int* __restrict__ cur,
                                             const int* __restrict__ part,
                                             int M, int total) {
    int base = blockIdx.x * 2048 + threadIdx.x * 8;
    int p = part[blockIdx.x];
#pragma unroll
    for (int t = 0; t < 8; ++t) {
        int i = base + t;
        if (i < M) {
            int v = off[i] + p;
            off[i] = v;
            cur[i] = v;
        }
    }
    if (blockIdx.x == 0 && threadIdx.x == 0) off[M] = total;
}

__global__ __launch_bounds__(256) void fill_kernel(const int* __restrict__ ep,
                                                   const int* __restrict__ en,
                                                   int* __restrict__ cur,
                                                   int* __restrict__ ent,
                                                   int N, int E) {
    int i = blockIdx.x * blockDim.x + threadIdx.x;
    if (i < E) {
        int r = ep[i], c = ep[E + i];
        ent[atomicAdd(&cur[0 * N + r], 1)] = c;
        ent[atomicAdd(&cur[1 * N + c], 1)] = r;
    } else if (i < 2 * E) {
        int j = i - E;
        int r = en[j], c = en[E + j];
        ent[atomicAdd(&cur[2 * N + r], 1)] = c;
        ent[atomicAdd(&cur[3 * N + c], 1)] = r;
    }
}

// ---------------------------------------------------------------------------
// CSR aggregate: one wave per (node n, slot k). 4-way unrolled, masked tail.
//   outs[n][64k + lane] = sum_{j in seg(k,n)} h16[ent[j]][lane] * score
//   score = exp(tanh(s[n][2k] + s[dst][2k+1] + att_b[k]))
// ---------------------------------------------------------------------------
__global__ __launch_bounds__(256) void aggregate(const __half* __restrict__ h16,
                                                 const float* __restrict__ s,
                                                 const int* __restrict__ off,
                                                 const int* __restrict__ ent,
                                                 const float* __restrict__ att_b_l,
                                                 float* __restrict__ outs, int N) {
    int n = blockIdx.x;
    int k = threadIdx.x >> 6;
    int lane = threadIdx.x & 63;
    int beg = off[k * N + n];
    int end = off[k * N + n + 1];
    float s1 = s[(size_t)n * 8 + 2 * k] + att_b_l[k];
    float acc = 0.f;
    for (int j = beg; j < end; j += 4) {
        int e1 = end - 1;
        int j1 = min(j + 1, e1), j2 = min(j + 2, e1), j3 = min(j + 3, e1);
        // 4 independent index loads, then 4 independent row gathers in flight
        int d0 = ent[j], d1 = ent[j1], d2 = ent[j2], d3 = ent[j3];
        float h0 = __half2float(h16[(size_t)d0 * 64 + lane]);
        float h1 = __half2float(h16[(size_t)d1 * 64 + lane]);
        float h2 = __half2float(h16[(size_t)d2 * 64 + lane]);
        float h3 = __half2float(h16[(size_t)d3 * 64 + lane]);
        float t0 = s[(size_t)d0 * 8 + 2 * k + 1];
        float t1 = s[(size_t)d1 * 8 + 2 * k + 1];
        float t2 = s[(size_t)d2 * 8 + 2 * k + 1];
        float t3 = s[(size_t)d3 * 8 + 2 * k + 1];
        float w0 = expf(tanhf(s1 + t0));
        float w1 = expf(tanhf(s1 + t1));
        float w2 = expf(tanhf(s1 + t2));
        float w3 = expf(tanhf(s1 + t3));
        acc += h0 * w0;
        acc += (j + 1 < end) ? h1 * w1 : 0.f;
        acc += (j + 2 < end) ? h2 * w2 : 0.f;
        acc += (j + 3 < end) ? h3 * w3 : 0.f;
    }
    outs[(size_t)n * 256 + k * 64 + lane] = acc;
}

// ---------------------------------------------------------------------------
// Head gather: x12[b] = [zc[idx1[b]], zc[idx2[b]]], x21[b] = swapped.
// ---------------------------------------------------------------------------
__global__ __launch_bounds__(256) void gather_heads(const float* __restrict__ emb0,
                                                    const float* __restrict__ emb1,
                                                    const int* __restrict__ idx1,
                                                    const int* __restrict__ idx2,
                                                    float* __restrict__ x12,
                                                    float* __restrict__ x21, int B) {
    int b = blockIdx.x;
    int j = threadIdx.x;
    int i1 = idx1[b], i2 = idx2[b];
    int seg = j >> 6, o = j & 63;
    const float* e = (seg & 1) ? emb1 : emb0;
    int n12 = (seg < 2) ? i1 : i2;
    int n21 = (seg < 2) ? i2 : i1;
    x12[(size_t)b * 256 + j] = e[(size_t)n12 * 64 + o];
    x21[(size_t)b * 256 + j] = e[(size_t)n21 * 64 + o];
}

// ---------------------------------------------------------------------------
// Final tiny GEMM: out[nrows x 2] = Z[nrows x 64] @ W[64 x 2] + bias
// ---------------------------------------------------------------------------
__global__ __launch_bounds__(256) void gemm_m2(const float* __restrict__ Z,
                                               const float* __restrict__ W,
                                               const float* __restrict__ bias,
                                               float* __restrict__ out, int nrows) {
    int row = blockIdx.x * blockDim.x + threadIdx.x;
    if (row >= nrows) return;
    float acc0 = bias[0], acc1 = bias[1];
#pragma unroll
    for (int kk = 0; kk < 64; ++kk) {
        float v = Z[(size_t)row * 64 + kk];
        acc0 += v * W[kk * 2 + 0];
        acc1 += v * W[kk * 2 + 1];
    }
    out[(size_t)row * 2 + 0] = acc0;
    out[(size_t)row * 2 + 1] = acc1;
}

static inline int cdiv(int a, int b) { return (a + b - 1) / b; }

extern "C" void kernel_launch(void* const* d_in, const int* in_sizes, int n_in,
                              void* d_out, int out_size, void* d_ws, size_t ws_size,
                              hipStream_t stream) {
    const float* x       = (const float*)d_in[0];
    const int* edge_pos  = (const int*)d_in[1];
    const int* edge_neg  = (const int*)d_in[2];
    const int* idx1      = (const int*)d_in[3];
    const int* idx2      = (const int*)d_in[4];
    const float* lin_w0  = (const float*)d_in[5];
    const float* lin_b0  = (const float*)d_in[6];
    const float* lin_w1  = (const float*)d_in[7];
    const float* lin_b1  = (const float*)d_in[8];
    const float* att_w   = (const float*)d_in[9];   // (2,4,128)
    const float* att_b   = (const float*)d_in[10];  // (2,4)
    const float* cat_w   = (const float*)d_in[11];  // (2,256,64)
    const float* cat_b   = (const float*)d_in[12];  // (2,64)
    const float* sw1 = (const float*)d_in[13];
    const float* sb1 = (const float*)d_in[14];
    const float* sw2 = (const float*)d_in[15];
    const float* sb2 = (const float*)d_in[16];
    const float* sw3 = (const float*)d_in[17];
    const float* sb3 = (const float*)d_in[18];
    const float* sw4 = (const float*)d_in[19];
    const float* sb4 = (const float*)d_in[20];
    const float* dw1 = (const float*)d_in[21];
    const float* db1 = (const float*)d_in[22];
    const float* dw2 = (const float*)d_in[23];
    const float* db2 = (const float*)d_in[24];
    float* out = (float*)d_out;

    const int N = in_sizes[0] / 64;  // 100000
    const int E = in_sizes[1] / 2;   // 800000
    const int B = in_sizes[3];       // 4096

    // -------- workspace layout (same float offsets as round 3) --------
    float* ws = (float*)d_ws;
    __half* h16 = (__half*)ws;                 // fp16 h in the old h slot (N*64 f32)
    float* outs = ws + (size_t)N * 64;         // N*256
    float* sbuf = outs + (size_t)N * 256;      // N*8
    float* emb0 = sbuf + (size_t)N * 8;        // N*64
    float* emb1 = emb0 + (size_t)N * 64;       // N*64 (CSR overlays until written)

    // CSR overlay inside emb1 region (dead until final cat-GEMM):
    int* cnt  = (int*)emb1;
    int* off  = cnt + (size_t)4 * N;
    int* cur  = off + (size_t)4 * N + 1;
    int* ent  = cur + (size_t)4 * N;
    int* part = ent + (size_t)4 * E;

    // heads overlay the (dead after GNN) h slot:
    float* x12 = ws;                     // B*256
    float* x21 = x12 + (size_t)B * 256;  // B*256
    float* hsA = x21 + (size_t)B * 256;  // B*64
    float* hsB = hsA + (size_t)B * 64;   // B*64

    const int gemm_blocks_N = cdiv(N, 64);
    const int gemm_blocks_B = cdiv(B, 64);
    const int s_blocks = cdiv(N, 4);        // 4 waves / block
    const int eg_blocks = cdiv(2 * E, 256); // count / fill
    const int M4 = 4 * N;
    const int scan_blocks = cdiv(M4, 2048);

    // -------- build CSR (shared by both layers) --------
    hipMemsetAsync(cnt, 0, (size_t)M4 * sizeof(int), stream);
    count_kernel<<<eg_blocks, 256, 0, stream>>>(edge_pos, edge_neg, cnt, N, E);
    scan1<<<scan_blocks, 256, 0, stream>>>(cnt, off, part, M4);
    scan1<<<1, 256, 0, stream>>>(part, part, nullptr, scan_blocks);
    scan3<<<scan_blocks, 256, 0, stream>>>(off, cur, part, M4, 4 * E);
    fill_kernel<<<eg_blocks, 256, 0, stream>>>(edge_pos, edge_neg, cur, ent, N, E);

    // -------- GNN layers --------
    for (int l = 0; l < 2; ++l) {
        const float* zin = (l == 0) ? x : emb0;
        const float* lw = (l == 0) ? lin_w0 : lin_w1;
        const float* lb = (l == 0) ? lin_b0 : lin_b1;
        gemm64<0, true><<<gemm_blocks_N, 256, 0, stream>>>(zin, lw, lb, h16, N, 64);
        s_kernel<<<s_blocks, 256, 0, stream>>>(h16, att_w + (size_t)l * 512, sbuf, N);
        aggregate<<<N, 256, 0, stream>>>(h16, sbuf, off, ent,
                                         att_b + (size_t)l * 4, outs, N);
        float* embl = (l == 0) ? emb0 : emb1;
        gemm64<2, false><<<gemm_blocks_N, 256, 0, stream>>>(outs, cat_w + (size_t)l * 16384,
                                                            cat_b + (size_t)l * 64, embl, N, 256);
    }

    // -------- heads --------
    gather_heads<<<B, 256, 0, stream>>>(emb0, emb1, idx1, idx2, x12, x21, B);

    gemm64<1, false><<<gemm_blocks_B, 256, 0, stream>>>(x12, sw1, sb1, hsA, B, 256);
    gemm64<1, false><<<gemm_blocks_B, 256, 0, stream>>>(hsA, sw2, sb2, hsB, B, 64);
    gemm64<1, false><<<gemm_blocks_B, 256, 0, stream>>>(hsB, sw3, sb3, hsA, B, 64);
    gemm_m2<<<cdiv(B, 256), 256, 0, stream>>>(hsA, sw4, sb4, out, B);

    gemm64<1, false><<<gemm_blocks_B, 256, 0, stream>>>(x12, dw1, db1, hsB, B, 256);
    gemm_m2<<<cdiv(B, 256), 256, 0, stream>>>(hsB, dw2, db2, out + (size_t)B * 2, B);
    gemm64<1, false><<<gemm_blocks_B, 256, 0, stream>>>(x21, dw1, db1, hsB, B, 256);
    gemm_m2<<<cdiv(B, 256), 256, 0, stream>>>(hsB, dw2, db2, out + (size_t)B * 4, B);
}

// Round 5
// 1293.838 us; speedup vs baseline: 1.8101x; 1.4362x over previous
//
#include <hip/hip_runtime.h>
#include <hip/hip_bf16.h>
#include <hip/hip_fp16.h>
#include <cstdint>
#include <cstddef>

// ---------------------------------------------------------------------------
// Tiled fp32 GEMM: out[nrows x 64] = act(Z[nrows x K] @ W[K x 64] + bias)
// ACT: 0=none, 1=relu, 2=tanh. H16: write __half output instead of float.
// Block 256 threads -> 64x64 tile, 4x4 per thread. float4 staging,
// zt transposed [k][row] (pad 68) so inner loop = 2x ds_read_b128 + 16 FMA.
// ---------------------------------------------------------------------------
template <int ACT, bool H16>
__global__ __launch_bounds__(256) void gemm64(const float* __restrict__ Z,
                                              const float* __restrict__ W,
                                              const float* __restrict__ bias,
                                              void* __restrict__ outp,
                                              int nrows, int K) {
    __shared__ float zt[64][68];  // [k][row]
    __shared__ float wt[64][68];  // [k][col]
    const int row0 = blockIdx.x * 64;
    const int tx = threadIdx.x & 15;   // 16 col groups
    const int ty = threadIdx.x >> 4;   // 16 row groups
    float acc[4][4] = {};

    for (int kb = 0; kb < K; kb += 64) {
#pragma unroll
        for (int i = 0; i < 4; ++i) {
            int v = threadIdx.x + 256 * i;  // 0..1023 float4 slots
            int rr = v >> 4;                // 0..63
            int c4 = (v & 15) * 4;
            int gr = row0 + rr;
            float4 zv = make_float4(0.f, 0.f, 0.f, 0.f);
            if (gr < nrows) zv = *(const float4*)&Z[(size_t)gr * K + kb + c4];
            zt[c4 + 0][rr] = zv.x;
            zt[c4 + 1][rr] = zv.y;
            zt[c4 + 2][rr] = zv.z;
            zt[c4 + 3][rr] = zv.w;
            float4 wv = *(const float4*)&W[(size_t)(kb + rr) * 64 + c4];
            *(float4*)&wt[rr][c4] = wv;
        }
        __syncthreads();
#pragma unroll
        for (int kk = 0; kk < 64; ++kk) {
            float4 a = *(const float4*)&zt[kk][ty * 4];
            float4 b = *(const float4*)&wt[kk][tx * 4];
            float av[4] = {a.x, a.y, a.z, a.w};
            float bv[4] = {b.x, b.y, b.z, b.w};
#pragma unroll
            for (int i = 0; i < 4; ++i)
#pragma unroll
                for (int j = 0; j < 4; ++j) acc[i][j] += av[i] * bv[j];
        }
        __syncthreads();
    }

#pragma unroll
    for (int i = 0; i < 4; ++i) {
        int gr = row0 + ty * 4 + i;
        if (gr >= nrows) continue;
#pragma unroll
        for (int j = 0; j < 4; ++j) {
            float v = acc[i][j] + bias[tx * 4 + j];
            if (ACT == 1) v = fmaxf(v, 0.f);
            if (ACT == 2) v = tanhf(v);
            if (H16)
                ((__half*)outp)[(size_t)gr * 64 + tx * 4 + j] = __float2half_rn(v);
            else
                ((float*)outp)[(size_t)gr * 64 + tx * 4 + j] = v;
        }
    }
}

// ---------------------------------------------------------------------------
// Attention scalars from fp16 h: s[n][2k] = h[n].att_w[k][0:64], etc.
// One wave per node.
// ---------------------------------------------------------------------------
__global__ __launch_bounds__(256) void s_kernel(const __half* __restrict__ h16,
                                                const float* __restrict__ att_w_l,
                                                float* __restrict__ s, int nnodes) {
    int wid = (int)((blockIdx.x * (size_t)blockDim.x + threadIdx.x) >> 6);
    int lane = threadIdx.x & 63;
    if (wid >= nnodes) return;
    float hv = __half2float(h16[(size_t)wid * 64 + lane]);
#pragma unroll
    for (int k = 0; k < 4; ++k) {
        float plo = hv * att_w_l[k * 128 + lane];
        float phi = hv * att_w_l[k * 128 + 64 + lane];
#pragma unroll
        for (int off = 32; off >= 1; off >>= 1) {
            plo += __shfl_xor(plo, off);
            phi += __shfl_xor(phi, off);
        }
        if (lane == 0) {
            s[(size_t)wid * 8 + 2 * k] = plo;
            s[(size_t)wid * 8 + 2 * k + 1] = phi;
        }
    }
}

// ---------------------------------------------------------------------------
// CSR build, 4 directed graphs (slot k, node n) -> flat k*N+n.
// count_kernel: histogram + per-edge rank (atomic return), rank stored
// sequentially so fill needs no atomics.
// ---------------------------------------------------------------------------
__global__ __launch_bounds__(256) void count_kernel(const int* __restrict__ ep,
                                                    const int* __restrict__ en,
                                                    int* __restrict__ cnt,
                                                    int* __restrict__ rnk,
                                                    int N, int E) {
    int i = blockIdx.x * blockDim.x + threadIdx.x;
    if (i < E) {
        int r = ep[i], c = ep[E + i];
        rnk[i]     = atomicAdd(&cnt[0 * N + r], 1);
        rnk[E + i] = atomicAdd(&cnt[1 * N + c], 1);
    } else if (i < 2 * E) {
        int j = i - E;
        int r = en[j], c = en[E + j];
        rnk[2 * E + j] = atomicAdd(&cnt[2 * N + r], 1);
        rnk[3 * E + j] = atomicAdd(&cnt[3 * N + c], 1);
    }
}

// Exclusive scan, 3-kernel hierarchy. 256 thr x 8 elem = 2048/block.
__global__ __launch_bounds__(256) void scan1(const int* __restrict__ in,
                                             int* __restrict__ out,
                                             int* __restrict__ part, int M) {
    __shared__ int ts[256];
    int base = blockIdx.x * 2048 + threadIdx.x * 8;
    int v[8];
    int run = 0;
#pragma unroll
    for (int t = 0; t < 8; ++t) {
        int x = (base + t < M) ? in[base + t] : 0;
        v[t] = run;
        run += x;
    }
    ts[threadIdx.x] = run;
    __syncthreads();
    for (int off = 1; off < 256; off <<= 1) {
        int t = (threadIdx.x >= off) ? ts[threadIdx.x - off] : 0;
        __syncthreads();
        ts[threadIdx.x] += t;
        __syncthreads();
    }
    int texcl = ts[threadIdx.x] - run;
    if (part && threadIdx.x == 255) part[blockIdx.x] = ts[255];
#pragma unroll
    for (int t = 0; t < 8; ++t)
        if (base + t < M) out[base + t] = v[t] + texcl;
}

// add block offsets + sentinel
__global__ __launch_bounds__(256) void scan3(int* __restrict__ off,
                                             const int* __restrict__ part,
                                             int M, int total) {
    int base = blockIdx.x * 2048 + threadIdx.x * 8;
    int p = part[blockIdx.x];
#pragma unroll
    for (int t = 0; t < 8; ++t) {
        int i = base + t;
        if (i < M) off[i] += p;
    }
    if (blockIdx.x == 0 && threadIdx.x == 0) off[M] = total;
}

// ---------------------------------------------------------------------------
// Bucketed fill: blockIdx.y = bucket over ent positions; each pass writes
// only positions in a 1.6MB window (L2-resident) -> full-line writebacks.
// No atomics (pos = off[slot] + rank).
// ---------------------------------------------------------------------------
__global__ __launch_bounds__(256) void fill_bucket(const int* __restrict__ ep,
                                                   const int* __restrict__ en,
                                                   const int* __restrict__ off,
                                                   const int* __restrict__ rnk,
                                                   int* __restrict__ ent,
                                                   int N, int E, int bsz) {
    int i = blockIdx.x * blockDim.x + threadIdx.x;
    int lo = blockIdx.y * bsz, hi = lo + bsz;
    if (i < E) {
        int r = ep[i], c = ep[E + i];
        int p0 = off[0 * N + r] + rnk[i];
        if (p0 >= lo && p0 < hi) ent[p0] = c;
        int p1 = off[1 * N + c] + rnk[E + i];
        if (p1 >= lo && p1 < hi) ent[p1] = r;
    } else if (i < 2 * E) {
        int j = i - E;
        int r = en[j], c = en[E + j];
        int p2 = off[2 * N + r] + rnk[2 * E + j];
        if (p2 >= lo && p2 < hi) ent[p2] = c;
        int p3 = off[3 * N + c] + rnk[3 * E + j];
        if (p3 >= lo && p3 < hi) ent[p3] = r;
    }
}

// ---------------------------------------------------------------------------
// CSR aggregate: one wave per (node n, slot k). 8-way unrolled, masked tail.
//   outs[n][64k + lane] = sum_{j in seg(k,n)} h16[ent[j]][lane] * score
//   score = exp(tanh(s[n][2k] + s[dst][2k+1] + att_b[k]))
// ---------------------------------------------------------------------------
__global__ __launch_bounds__(256) void aggregate(const __half* __restrict__ h16,
                                                 const float* __restrict__ s,
                                                 const int* __restrict__ off,
                                                 const int* __restrict__ ent,
                                                 const float* __restrict__ att_b_l,
                                                 float* __restrict__ outs, int N) {
    int n = blockIdx.x;
    int k = threadIdx.x >> 6;
    int lane = threadIdx.x & 63;
    int beg = off[k * N + n];
    int end = off[k * N + n + 1];
    float s1 = s[(size_t)n * 8 + 2 * k] + att_b_l[k];
    float acc = 0.f;
    for (int j = beg; j < end; j += 8) {
        int e1 = end - 1;
        int d[8];
        float hh[8], t2[8];
#pragma unroll
        for (int t = 0; t < 8; ++t) {
            int jt = min(j + t, e1);
            d[t] = ent[jt];
        }
#pragma unroll
        for (int t = 0; t < 8; ++t) hh[t] = __half2float(h16[(size_t)d[t] * 64 + lane]);
#pragma unroll
        for (int t = 0; t < 8; ++t) t2[t] = s[(size_t)d[t] * 8 + 2 * k + 1];
#pragma unroll
        for (int t = 0; t < 8; ++t) {
            float w = expf(tanhf(s1 + t2[t]));
            acc += (t == 0 || j + t < end) ? hh[t] * w : 0.f;
        }
    }
    outs[(size_t)n * 256 + k * 64 + lane] = acc;
}

// ---------------------------------------------------------------------------
// Head gather: x12[b] = [zc[idx1[b]], zc[idx2[b]]], x21[b] = swapped.
// ---------------------------------------------------------------------------
__global__ __launch_bounds__(256) void gather_heads(const float* __restrict__ emb0,
                                                    const float* __restrict__ emb1,
                                                    const int* __restrict__ idx1,
                                                    const int* __restrict__ idx2,
                                                    float* __restrict__ x12,
                                                    float* __restrict__ x21, int B) {
    int b = blockIdx.x;
    int j = threadIdx.x;
    int i1 = idx1[b], i2 = idx2[b];
    int seg = j >> 6, o = j & 63;
    const float* e = (seg & 1) ? emb1 : emb0;
    int n12 = (seg < 2) ? i1 : i2;
    int n21 = (seg < 2) ? i2 : i1;
    x12[(size_t)b * 256 + j] = e[(size_t)n12 * 64 + o];
    x21[(size_t)b * 256 + j] = e[(size_t)n21 * 64 + o];
}

// ---------------------------------------------------------------------------
// Final tiny GEMM: out[nrows x 2] = Z[nrows x 64] @ W[64 x 2] + bias
// ---------------------------------------------------------------------------
__global__ __launch_bounds__(256) void gemm_m2(const float* __restrict__ Z,
                                               const float* __restrict__ W,
                                               const float* __restrict__ bias,
                                               float* __restrict__ out, int nrows) {
    int row = blockIdx.x * blockDim.x + threadIdx.x;
    if (row >= nrows) return;
    float acc0 = bias[0], acc1 = bias[1];
#pragma unroll
    for (int kk = 0; kk < 64; ++kk) {
        float v = Z[(size_t)row * 64 + kk];
        acc0 += v * W[kk * 2 + 0];
        acc1 += v * W[kk * 2 + 1];
    }
    out[(size_t)row * 2 + 0] = acc0;
    out[(size_t)row * 2 + 1] = acc1;
}

static inline int cdiv(int a, int b) { return (a + b - 1) / b; }

extern "C" void kernel_launch(void* const* d_in, const int* in_sizes, int n_in,
                              void* d_out, int out_size, void* d_ws, size_t ws_size,
                              hipStream_t stream) {
    const float* x       = (const float*)d_in[0];
    const int* edge_pos  = (const int*)d_in[1];
    const int* edge_neg  = (const int*)d_in[2];
    const int* idx1      = (const int*)d_in[3];
    const int* idx2      = (const int*)d_in[4];
    const float* lin_w0  = (const float*)d_in[5];
    const float* lin_b0  = (const float*)d_in[6];
    const float* lin_w1  = (const float*)d_in[7];
    const float* lin_b1  = (const float*)d_in[8];
    const float* att_w   = (const float*)d_in[9];   // (2,4,128)
    const float* att_b   = (const float*)d_in[10];  // (2,4)
    const float* cat_w   = (const float*)d_in[11];  // (2,256,64)
    const float* cat_b   = (const float*)d_in[12];  // (2,64)
    const float* sw1 = (const float*)d_in[13];
    const float* sb1 = (const float*)d_in[14];
    const float* sw2 = (const float*)d_in[15];
    const float* sb2 = (const float*)d_in[16];
    const float* sw3 = (const float*)d_in[17];
    const float* sb3 = (const float*)d_in[18];
    const float* sw4 = (const float*)d_in[19];
    const float* sb4 = (const float*)d_in[20];
    const float* dw1 = (const float*)d_in[21];
    const float* db1 = (const float*)d_in[22];
    const float* dw2 = (const float*)d_in[23];
    const float* db2 = (const float*)d_in[24];
    float* out = (float*)d_out;

    const int N = in_sizes[0] / 64;  // 100000
    const int E = in_sizes[1] / 2;   // 800000
    const int B = in_sizes[3];       // 4096
    const int NB = 8;                // fill buckets

    // -------- workspace layout --------
    float* ws = (float*)d_ws;
    __half* h16 = (__half*)ws;                 // fp16 h (in old N*64-f32 slot)
    float* outs = ws + (size_t)N * 64;         // N*256
    float* sbuf = outs + (size_t)N * 256;      // N*8
    float* emb0 = sbuf + (size_t)N * 8;        // N*64
    float* emb1 = emb0 + (size_t)N * 64;       // N*64

    // persistent CSR in emb1 region (dead until final cat-GEMM writes it):
    int* ent = (int*)emb1;                     // 4E ints
    int* off = ent + (size_t)4 * E;            // 4N+1 ints
    // build-temp arrays in outs region (dead until first aggregate):
    int* cnt  = (int*)outs;                    // 4N
    int* rnk  = cnt + (size_t)4 * N;           // 4E
    int* part = rnk + (size_t)4 * E;           // scan partials

    // heads overlay the (dead after GNN) h slot:
    float* x12 = ws;                     // B*256
    float* x21 = x12 + (size_t)B * 256;  // B*256
    float* hsA = x21 + (size_t)B * 256;  // B*64
    float* hsB = hsA + (size_t)B * 64;   // B*64

    const int gemm_blocks_N = cdiv(N, 64);
    const int gemm_blocks_B = cdiv(B, 64);
    const int s_blocks = cdiv(N, 4);        // 4 waves / block
    const int eg_blocks = cdiv(2 * E, 256);
    const int M4 = 4 * N;
    const int scan_blocks = cdiv(M4, 2048);
    const int bsz = cdiv(4 * E, NB);

    // -------- build CSR (shared by both layers) --------
    hipMemsetAsync(cnt, 0, (size_t)M4 * sizeof(int), stream);
    count_kernel<<<eg_blocks, 256, 0, stream>>>(edge_pos, edge_neg, cnt, rnk, N, E);
    scan1<<<scan_blocks, 256, 0, stream>>>(cnt, off, part, M4);
    scan1<<<1, 256, 0, stream>>>(part, part, nullptr, scan_blocks);
    scan3<<<scan_blocks, 256, 0, stream>>>(off, part, M4, 4 * E);
    fill_bucket<<<dim3(eg_blocks, NB), 256, 0, stream>>>(edge_pos, edge_neg, off,
                                                         rnk, ent, N, E, bsz);

    // -------- GNN layers --------
    for (int l = 0; l < 2; ++l) {
        const float* zin = (l == 0) ? x : emb0;
        const float* lw = (l == 0) ? lin_w0 : lin_w1;
        const float* lb = (l == 0) ? lin_b0 : lin_b1;
        gemm64<0, true><<<gemm_blocks_N, 256, 0, stream>>>(zin, lw, lb, h16, N, 64);
        s_kernel<<<s_blocks, 256, 0, stream>>>(h16, att_w + (size_t)l * 512, sbuf, N);
        aggregate<<<N, 256, 0, stream>>>(h16, sbuf, off, ent,
                                         att_b + (size_t)l * 4, outs, N);
        float* embl = (l == 0) ? emb0 : emb1;
        gemm64<2, false><<<gemm_blocks_N, 256, 0, stream>>>(outs, cat_w + (size_t)l * 16384,
                                                            cat_b + (size_t)l * 64, embl, N, 256);
    }

    // -------- heads --------
    gather_heads<<<B, 256, 0, stream>>>(emb0, emb1, idx1, idx2, x12, x21, B);

    gemm64<1, false><<<gemm_blocks_B, 256, 0, stream>>>(x12, sw1, sb1, hsA, B, 256);
    gemm64<1, false><<<gemm_blocks_B, 256, 0, stream>>>(hsA, sw2, sb2, hsB, B, 64);
    gemm64<1, false><<<gemm_blocks_B, 256, 0, stream>>>(hsB, sw3, sb3, hsA, B, 64);
    gemm_m2<<<cdiv(B, 256), 256, 0, stream>>>(hsA, sw4, sb4, out, B);

    gemm64<1, false><<<gemm_blocks_B, 256, 0, stream>>>(x12, dw1, db1, hsB, B, 256);
    gemm_m2<<<cdiv(B, 256), 256, 0, stream>>>(hsB, dw2, db2, out + (size_t)B * 2, B);
    gemm64<1, false><<<gemm_blocks_B, 256, 0, stream>>>(x21, dw1, db1, hsB, B, 256);
    gemm_m2<<<cdiv(B, 256), 256, 0, stream>>>(hsB, dw2, db2, out + (size_t)B * 4, B);
}

// Round 6
// 1044.868 us; speedup vs baseline: 2.2414x; 1.2383x over previous
//
#include <hip/hip_runtime.h>
#include <hip/hip_bf16.h>
#include <hip/hip_fp16.h>
#include <cstdint>
#include <cstddef>

// ---------------------------------------------------------------------------
// Tiled GEMM: out[nrows x 64] = act(Z[nrows x K] @ W[K x 64] + bias)
// ACT: 0=none, 1=relu, 2=tanh. H16OUT: __half output. H16IN: __half input Z.
// Block 256 -> 64x64 tile, 4x4 per thread. Vectorized staging,
// zt transposed [k][row] (pad 68) so inner loop = 2x ds_read_b128 + 16 FMA.
// ---------------------------------------------------------------------------
template <int ACT, bool H16OUT, bool H16IN>
__global__ __launch_bounds__(256) void gemm64(const void* __restrict__ Zp,
                                              const float* __restrict__ W,
                                              const float* __restrict__ bias,
                                              void* __restrict__ outp,
                                              int nrows, int K) {
    __shared__ float zt[64][68];  // [k][row]
    __shared__ float wt[64][68];  // [k][col]
    const int row0 = blockIdx.x * 64;
    const int tx = threadIdx.x & 15;   // 16 col groups
    const int ty = threadIdx.x >> 4;   // 16 row groups
    float acc[4][4] = {};

    for (int kb = 0; kb < K; kb += 64) {
#pragma unroll
        for (int i = 0; i < 4; ++i) {
            int v = threadIdx.x + 256 * i;  // 0..1023 4-elem slots
            int rr = v >> 4;                // 0..63
            int c4 = (v & 15) * 4;
            int gr = row0 + rr;
            float4 zv = make_float4(0.f, 0.f, 0.f, 0.f);
            if (gr < nrows) {
                if (H16IN) {
                    const __half* Zh = (const __half*)Zp;
                    __half2 a = *(const __half2*)&Zh[(size_t)gr * K + kb + c4];
                    __half2 b = *(const __half2*)&Zh[(size_t)gr * K + kb + c4 + 2];
                    zv = make_float4(__half2float(a.x), __half2float(a.y),
                                     __half2float(b.x), __half2float(b.y));
                } else {
                    zv = *(const float4*)&((const float*)Zp)[(size_t)gr * K + kb + c4];
                }
            }
            zt[c4 + 0][rr] = zv.x;
            zt[c4 + 1][rr] = zv.y;
            zt[c4 + 2][rr] = zv.z;
            zt[c4 + 3][rr] = zv.w;
            float4 wv = *(const float4*)&W[(size_t)(kb + rr) * 64 + c4];
            *(float4*)&wt[rr][c4] = wv;
        }
        __syncthreads();
#pragma unroll
        for (int kk = 0; kk < 64; ++kk) {
            float4 a = *(const float4*)&zt[kk][ty * 4];
            float4 b = *(const float4*)&wt[kk][tx * 4];
            float av[4] = {a.x, a.y, a.z, a.w};
            float bv[4] = {b.x, b.y, b.z, b.w};
#pragma unroll
            for (int i = 0; i < 4; ++i)
#pragma unroll
                for (int j = 0; j < 4; ++j) acc[i][j] += av[i] * bv[j];
        }
        __syncthreads();
    }

#pragma unroll
    for (int i = 0; i < 4; ++i) {
        int gr = row0 + ty * 4 + i;
        if (gr >= nrows) continue;
#pragma unroll
        for (int j = 0; j < 4; ++j) {
            float v = acc[i][j] + bias[tx * 4 + j];
            if (ACT == 1) v = fmaxf(v, 0.f);
            if (ACT == 2) v = tanhf(v);
            if (H16OUT)
                ((__half*)outp)[(size_t)gr * 64 + tx * 4 + j] = __float2half_rn(v);
            else
                ((float*)outp)[(size_t)gr * 64 + tx * 4 + j] = v;
        }
    }
}

// ---------------------------------------------------------------------------
// Attention scalars from fp16 h: s[n][2k] = h[n].att_w[k][0:64], etc.
// One wave per node.
// ---------------------------------------------------------------------------
__global__ __launch_bounds__(256) void s_kernel(const __half* __restrict__ h16,
                                                const float* __restrict__ att_w_l,
                                                float* __restrict__ s, int nnodes) {
    int wid = (int)((blockIdx.x * (size_t)blockDim.x + threadIdx.x) >> 6);
    int lane = threadIdx.x & 63;
    if (wid >= nnodes) return;
    float hv = __half2float(h16[(size_t)wid * 64 + lane]);
#pragma unroll
    for (int k = 0; k < 4; ++k) {
        float plo = hv * att_w_l[k * 128 + lane];
        float phi = hv * att_w_l[k * 128 + 64 + lane];
#pragma unroll
        for (int off = 32; off >= 1; off >>= 1) {
            plo += __shfl_xor(plo, off);
            phi += __shfl_xor(phi, off);
        }
        if (lane == 0) {
            s[(size_t)wid * 8 + 2 * k] = plo;
            s[(size_t)wid * 8 + 2 * k + 1] = phi;
        }
    }
}

// ---------------------------------------------------------------------------
// CSR build, 4 directed graphs (slot k, node n) -> flat k*N+n.
// count_kernel: histogram + per-edge rank (atomic return).
// ---------------------------------------------------------------------------
__global__ __launch_bounds__(256) void count_kernel(const int* __restrict__ ep,
                                                    const int* __restrict__ en,
                                                    int* __restrict__ cnt,
                                                    int* __restrict__ rnk,
                                                    int N, int E) {
    int i = blockIdx.x * blockDim.x + threadIdx.x;
    if (i < E) {
        int r = ep[i], c = ep[E + i];
        rnk[i]     = atomicAdd(&cnt[0 * N + r], 1);
        rnk[E + i] = atomicAdd(&cnt[1 * N + c], 1);
    } else if (i < 2 * E) {
        int j = i - E;
        int r = en[j], c = en[E + j];
        rnk[2 * E + j] = atomicAdd(&cnt[2 * N + r], 1);
        rnk[3 * E + j] = atomicAdd(&cnt[3 * N + c], 1);
    }
}

// Exclusive scan, 3-kernel hierarchy. 256 thr x 8 elem = 2048/block.
__global__ __launch_bounds__(256) void scan1(const int* __restrict__ in,
                                             int* __restrict__ out,
                                             int* __restrict__ part, int M) {
    __shared__ int ts[256];
    int base = blockIdx.x * 2048 + threadIdx.x * 8;
    int v[8];
    int run = 0;
#pragma unroll
    for (int t = 0; t < 8; ++t) {
        int x = (base + t < M) ? in[base + t] : 0;
        v[t] = run;
        run += x;
    }
    ts[threadIdx.x] = run;
    __syncthreads();
    for (int off = 1; off < 256; off <<= 1) {
        int t = (threadIdx.x >= off) ? ts[threadIdx.x - off] : 0;
        __syncthreads();
        ts[threadIdx.x] += t;
        __syncthreads();
    }
    int texcl = ts[threadIdx.x] - run;
    if (part && threadIdx.x == 255) part[blockIdx.x] = ts[255];
#pragma unroll
    for (int t = 0; t < 8; ++t)
        if (base + t < M) out[base + t] = v[t] + texcl;
}

// add block offsets + sentinel
__global__ __launch_bounds__(256) void scan3(int* __restrict__ off,
                                             const int* __restrict__ part,
                                             int M, int total) {
    int base = blockIdx.x * 2048 + threadIdx.x * 8;
    int p = part[blockIdx.x];
#pragma unroll
    for (int t = 0; t < 8; ++t) {
        int i = base + t;
        if (i < M) off[i] += p;
    }
    if (blockIdx.x == 0 && threadIdx.x == 0) off[M] = total;
}

// ---------------------------------------------------------------------------
// Bucketed fill: writes ent[pos]=dst and own[pos]=src for pos in an L2-sized
// window per pass. No atomics (pos = off[slot] + rank).
// ---------------------------------------------------------------------------
__global__ __launch_bounds__(256) void fill_bucket(const int* __restrict__ ep,
                                                   const int* __restrict__ en,
                                                   const int* __restrict__ off,
                                                   const int* __restrict__ rnk,
                                                   int* __restrict__ ent,
                                                   int* __restrict__ own,
                                                   int N, int E, int bsz) {
    int i = blockIdx.x * blockDim.x + threadIdx.x;
    int lo = blockIdx.y * bsz, hi = lo + bsz;
    if (i < E) {
        int r = ep[i], c = ep[E + i];
        int p0 = off[0 * N + r] + rnk[i];
        if (p0 >= lo && p0 < hi) { ent[p0] = c; own[p0] = r; }
        int p1 = off[1 * N + c] + rnk[E + i];
        if (p1 >= lo && p1 < hi) { ent[p1] = r; own[p1] = c; }
    } else if (i < 2 * E) {
        int j = i - E;
        int r = en[j], c = en[E + j];
        int p2 = off[2 * N + r] + rnk[2 * E + j];
        if (p2 >= lo && p2 < hi) { ent[p2] = c; own[p2] = r; }
        int p3 = off[3 * N + c] + rnk[3 * E + j];
        if (p3 >= lo && p3 < hi) { ent[p3] = r; own[p3] = c; }
    }
}

// ---------------------------------------------------------------------------
// Per-entry scores: score16[j] = fp16(exp(tanh(s[own][2k] + s[ent][2k+1] + b[k])))
// k recovered from j via segment boundaries off[N],off[2N],off[3N].
// ---------------------------------------------------------------------------
__global__ __launch_bounds__(256) void score_kernel(const int* __restrict__ ent,
                                                    const int* __restrict__ own,
                                                    const int* __restrict__ off,
                                                    const float* __restrict__ s,
                                                    const float* __restrict__ att_b_l,
                                                    __half* __restrict__ score16,
                                                    int N, int total) {
    int j = blockIdx.x * blockDim.x + threadIdx.x;
    if (j >= total) return;
    int b1 = off[N], b2 = off[2 * N], b3 = off[3 * N];
    int k = (j >= b1) + (j >= b2) + (j >= b3);
    int d = ent[j], o = own[j];
    float t = s[(size_t)o * 8 + 2 * k] + s[(size_t)d * 8 + 2 * k + 1] + att_b_l[k];
    score16[j] = __float2half_rn(expf(tanhf(t)));
}

// ---------------------------------------------------------------------------
// CSR aggregate: one wave per (node n, slot k). 8-way unrolled, masked tail.
//   outs16[n][64k + lane] = sum_{j in seg(k,n)} h16[ent[j]][lane] * score16[j]
// Pure gather + FMA (scores precomputed).
// ---------------------------------------------------------------------------
__global__ __launch_bounds__(256) void aggregate(const __half* __restrict__ h16,
                                                 const int* __restrict__ off,
                                                 const int* __restrict__ ent,
                                                 const __half* __restrict__ score16,
                                                 __half* __restrict__ outs16, int N) {
    int n = blockIdx.x;
    int k = threadIdx.x >> 6;
    int lane = threadIdx.x & 63;
    int beg = off[k * N + n];
    int end = off[k * N + n + 1];
    float acc = 0.f;
    for (int j = beg; j < end; j += 8) {
        int e1 = end - 1;
        int d[8];
        float hh[8], sc[8];
#pragma unroll
        for (int t = 0; t < 8; ++t) {
            int jt = min(j + t, e1);
            d[t] = ent[jt];
            sc[t] = __half2float(score16[jt]);
        }
#pragma unroll
        for (int t = 0; t < 8; ++t) hh[t] = __half2float(h16[(size_t)d[t] * 64 + lane]);
#pragma unroll
        for (int t = 0; t < 8; ++t)
            acc += (t == 0 || j + t < end) ? hh[t] * sc[t] : 0.f;
    }
    outs16[(size_t)n * 256 + k * 64 + lane] = __float2half_rn(acc);
}

// ---------------------------------------------------------------------------
// Head gather: x12[b] = [zc[idx1[b]], zc[idx2[b]]], x21[b] = swapped.
// ---------------------------------------------------------------------------
__global__ __launch_bounds__(256) void gather_heads(const float* __restrict__ emb0,
                                                    const float* __restrict__ emb1,
                                                    const int* __restrict__ idx1,
                                                    const int* __restrict__ idx2,
                                                    float* __restrict__ x12,
                                                    float* __restrict__ x21, int B) {
    int b = blockIdx.x;
    int j = threadIdx.x;
    int i1 = idx1[b], i2 = idx2[b];
    int seg = j >> 6, o = j & 63;
    const float* e = (seg & 1) ? emb1 : emb0;
    int n12 = (seg < 2) ? i1 : i2;
    int n21 = (seg < 2) ? i2 : i1;
    x12[(size_t)b * 256 + j] = e[(size_t)n12 * 64 + o];
    x21[(size_t)b * 256 + j] = e[(size_t)n21 * 64 + o];
}

// ---------------------------------------------------------------------------
// Final tiny GEMM: out[nrows x 2] = Z[nrows x 64] @ W[64 x 2] + bias
// ---------------------------------------------------------------------------
__global__ __launch_bounds__(256) void gemm_m2(const float* __restrict__ Z,
                                               const float* __restrict__ W,
                                               const float* __restrict__ bias,
                                               float* __restrict__ out, int nrows) {
    int row = blockIdx.x * blockDim.x + threadIdx.x;
    if (row >= nrows) return;
    float acc0 = bias[0], acc1 = bias[1];
#pragma unroll
    for (int kk = 0; kk < 64; ++kk) {
        float v = Z[(size_t)row * 64 + kk];
        acc0 += v * W[kk * 2 + 0];
        acc1 += v * W[kk * 2 + 1];
    }
    out[(size_t)row * 2 + 0] = acc0;
    out[(size_t)row * 2 + 1] = acc1;
}

static inline int cdiv(int a, int b) { return (a + b - 1) / b; }

extern "C" void kernel_launch(void* const* d_in, const int* in_sizes, int n_in,
                              void* d_out, int out_size, void* d_ws, size_t ws_size,
                              hipStream_t stream) {
    const float* x       = (const float*)d_in[0];
    const int* edge_pos  = (const int*)d_in[1];
    const int* edge_neg  = (const int*)d_in[2];
    const int* idx1      = (const int*)d_in[3];
    const int* idx2      = (const int*)d_in[4];
    const float* lin_w0  = (const float*)d_in[5];
    const float* lin_b0  = (const float*)d_in[6];
    const float* lin_w1  = (const float*)d_in[7];
    const float* lin_b1  = (const float*)d_in[8];
    const float* att_w   = (const float*)d_in[9];   // (2,4,128)
    const float* att_b   = (const float*)d_in[10];  // (2,4)
    const float* cat_w   = (const float*)d_in[11];  // (2,256,64)
    const float* cat_b   = (const float*)d_in[12];  // (2,64)
    const float* sw1 = (const float*)d_in[13];
    const float* sb1 = (const float*)d_in[14];
    const float* sw2 = (const float*)d_in[15];
    const float* sb2 = (const float*)d_in[16];
    const float* sw3 = (const float*)d_in[17];
    const float* sb3 = (const float*)d_in[18];
    const float* sw4 = (const float*)d_in[19];
    const float* sb4 = (const float*)d_in[20];
    const float* dw1 = (const float*)d_in[21];
    const float* db1 = (const float*)d_in[22];
    const float* dw2 = (const float*)d_in[23];
    const float* db2 = (const float*)d_in[24];
    float* out = (float*)d_out;

    const int N = in_sizes[0] / 64;  // 100000
    const int E = in_sizes[1] / 2;   // 800000
    const int B = in_sizes[3];       // 4096
    const int NB = 8;                // fill buckets

    // -------- workspace layout --------
    float* ws = (float*)d_ws;
    // Region A (old h slot, N*64 f32 = 25.6MB): h16 (12.8MB) + own (12.8MB)
    __half* h16 = (__half*)ws;
    int* own    = (int*)(ws + (size_t)N * 32);
    // Region B: outs16 (N*256 fp16 uses half of the N*256-f32 slot)
    float* outsR = ws + (size_t)N * 64;        // region base (N*256 f32 wide)
    __half* outs16 = (__half*)outsR;
    float* sbuf = outsR + (size_t)N * 256;     // N*8 f32
    float* emb0 = sbuf + (size_t)N * 8;        // N*64 f32
    float* emb1 = emb0 + (size_t)N * 64;       // N*64 f32

    // Region E (emb1, dead until final cat-GEMM): ent | off | score16
    int* ent = (int*)emb1;                          // 4E ints
    int* off = ent + (size_t)4 * E;                 // 4N+1 ints
    __half* score16 = (__half*)(off + (size_t)4 * N + 1);  // 4E halves

    // build temps in region B (dead until first aggregate):
    int* cnt  = (int*)outsR;                   // 4N
    int* rnk  = cnt + (size_t)4 * N;           // 4E
    int* part = rnk + (size_t)4 * E;           // scan partials

    // heads overlay region A after GNN:
    float* x12 = ws;                     // B*256
    float* x21 = x12 + (size_t)B * 256;  // B*256
    float* hsA = x21 + (size_t)B * 256;  // B*64
    float* hsB = hsA + (size_t)B * 64;   // B*64

    const int gemm_blocks_N = cdiv(N, 64);
    const int gemm_blocks_B = cdiv(B, 64);
    const int s_blocks = cdiv(N, 4);
    const int eg_blocks = cdiv(2 * E, 256);
    const int M4 = 4 * N;
    const int scan_blocks = cdiv(M4, 2048);
    const int bsz = cdiv(4 * E, NB);
    const int sc_blocks = cdiv(4 * E, 256);

    // -------- build CSR (shared by both layers) --------
    hipMemsetAsync(cnt, 0, (size_t)M4 * sizeof(int), stream);
    count_kernel<<<eg_blocks, 256, 0, stream>>>(edge_pos, edge_neg, cnt, rnk, N, E);
    scan1<<<scan_blocks, 256, 0, stream>>>(cnt, off, part, M4);
    scan1<<<1, 256, 0, stream>>>(part, part, nullptr, scan_blocks);
    scan3<<<scan_blocks, 256, 0, stream>>>(off, part, M4, 4 * E);
    fill_bucket<<<dim3(eg_blocks, NB), 256, 0, stream>>>(edge_pos, edge_neg, off,
                                                         rnk, ent, own, N, E, bsz);

    // -------- GNN layers --------
    for (int l = 0; l < 2; ++l) {
        const void* zin = (l == 0) ? (const void*)x : (const void*)emb0;
        const float* lw = (l == 0) ? lin_w0 : lin_w1;
        const float* lb = (l == 0) ? lin_b0 : lin_b1;
        gemm64<0, true, false><<<gemm_blocks_N, 256, 0, stream>>>(zin, lw, lb, h16, N, 64);
        s_kernel<<<s_blocks, 256, 0, stream>>>(h16, att_w + (size_t)l * 512, sbuf, N);
        score_kernel<<<sc_blocks, 256, 0, stream>>>(ent, own, off, sbuf,
                                                    att_b + (size_t)l * 4, score16,
                                                    N, 4 * E);
        aggregate<<<N, 256, 0, stream>>>(h16, off, ent, score16, outs16, N);
        float* embl = (l == 0) ? emb0 : emb1;
        gemm64<2, false, true><<<gemm_blocks_N, 256, 0, stream>>>(outs16,
                                                                  cat_w + (size_t)l * 16384,
                                                                  cat_b + (size_t)l * 64,
                                                                  embl, N, 256);
    }

    // -------- heads --------
    gather_heads<<<B, 256, 0, stream>>>(emb0, emb1, idx1, idx2, x12, x21, B);

    gemm64<1, false, false><<<gemm_blocks_B, 256, 0, stream>>>(x12, sw1, sb1, hsA, B, 256);
    gemm64<1, false, false><<<gemm_blocks_B, 256, 0, stream>>>(hsA, sw2, sb2, hsB, B, 64);
    gemm64<1, false, false><<<gemm_blocks_B, 256, 0, stream>>>(hsB, sw3, sb3, hsA, B, 64);
    gemm_m2<<<cdiv(B, 256), 256, 0, stream>>>(hsA, sw4, sb4, out, B);

    gemm64<1, false, false><<<gemm_blocks_B, 256, 0, stream>>>(x12, dw1, db1, hsB, B, 256);
    gemm_m2<<<cdiv(B, 256), 256, 0, stream>>>(hsB, dw2, db2, out + (size_t)B * 2, B);
    gemm64<1, false, false><<<gemm_blocks_B, 256, 0, stream>>>(x21, dw1, db1, hsB, B, 256);
    gemm_m2<<<cdiv(B, 256), 256, 0, stream>>>(hsB, dw2, db2, out + (size_t)B * 4, B);
}

// Round 8
// 1024.571 us; speedup vs baseline: 2.2858x; 1.0198x over previous
//
#include <hip/hip_runtime.h>
#include <hip/hip_bf16.h>
#include <hip/hip_fp16.h>
#include <cstdint>
#include <cstddef>

// ---------------------------------------------------------------------------
// Tiled GEMM: out[nrows x 64] = act(Z[nrows x K] @ W[K x 64] + bias)
// ACT: 0=none, 1=relu, 2=tanh. H16OUT: __half output. H16IN: __half input Z.
// Block 256 -> 64x64 tile, 4x4 per thread. Vectorized staging,
// zt transposed [k][row] (pad 68) so inner loop = 2x ds_read_b128 + 16 FMA.
// ---------------------------------------------------------------------------
template <int ACT, bool H16OUT, bool H16IN>
__global__ __launch_bounds__(256) void gemm64(const void* __restrict__ Zp,
                                              const float* __restrict__ W,
                                              const float* __restrict__ bias,
                                              void* __restrict__ outp,
                                              int nrows, int K) {
    __shared__ float zt[64][68];  // [k][row]
    __shared__ float wt[64][68];  // [k][col]
    const int row0 = blockIdx.x * 64;
    const int tx = threadIdx.x & 15;   // 16 col groups
    const int ty = threadIdx.x >> 4;   // 16 row groups
    float acc[4][4] = {};

    for (int kb = 0; kb < K; kb += 64) {
#pragma unroll
        for (int i = 0; i < 4; ++i) {
            int v = threadIdx.x + 256 * i;  // 0..1023 4-elem slots
            int rr = v >> 4;                // 0..63
            int c4 = (v & 15) * 4;
            int gr = row0 + rr;
            float4 zv = make_float4(0.f, 0.f, 0.f, 0.f);
            if (gr < nrows) {
                if (H16IN) {
                    const __half* Zh = (const __half*)Zp;
                    __half2 a = *(const __half2*)&Zh[(size_t)gr * K + kb + c4];
                    __half2 b = *(const __half2*)&Zh[(size_t)gr * K + kb + c4 + 2];
                    zv = make_float4(__half2float(a.x), __half2float(a.y),
                                     __half2float(b.x), __half2float(b.y));
                } else {
                    zv = *(const float4*)&((const float*)Zp)[(size_t)gr * K + kb + c4];
                }
            }
            zt[c4 + 0][rr] = zv.x;
            zt[c4 + 1][rr] = zv.y;
            zt[c4 + 2][rr] = zv.z;
            zt[c4 + 3][rr] = zv.w;
            float4 wv = *(const float4*)&W[(size_t)(kb + rr) * 64 + c4];
            *(float4*)&wt[rr][c4] = wv;
        }
        __syncthreads();
#pragma unroll
        for (int kk = 0; kk < 64; ++kk) {
            float4 a = *(const float4*)&zt[kk][ty * 4];
            float4 b = *(const float4*)&wt[kk][tx * 4];
            float av[4] = {a.x, a.y, a.z, a.w};
            float bv[4] = {b.x, b.y, b.z, b.w};
#pragma unroll
            for (int i = 0; i < 4; ++i)
#pragma unroll
                for (int j = 0; j < 4; ++j) acc[i][j] += av[i] * bv[j];
        }
        __syncthreads();
    }

#pragma unroll
    for (int i = 0; i < 4; ++i) {
        int gr = row0 + ty * 4 + i;
        if (gr >= nrows) continue;
#pragma unroll
        for (int j = 0; j < 4; ++j) {
            float v = acc[i][j] + bias[tx * 4 + j];
            if (ACT == 1) v = fmaxf(v, 0.f);
            if (ACT == 2) v = tanhf(v);
            if (H16OUT)
                ((__half*)outp)[(size_t)gr * 64 + tx * 4 + j] = __float2half_rn(v);
            else
                ((float*)outp)[(size_t)gr * 64 + tx * 4 + j] = v;
        }
    }
}

// ---------------------------------------------------------------------------
// Attention scalars from fp16 h: s[n][2k] = h[n].att_w[k][0:64], etc.
// One wave per node.
// ---------------------------------------------------------------------------
__global__ __launch_bounds__(256) void s_kernel(const __half* __restrict__ h16,
                                                const float* __restrict__ att_w_l,
                                                float* __restrict__ s, int nnodes) {
    int wid = (int)((blockIdx.x * (size_t)blockDim.x + threadIdx.x) >> 6);
    int lane = threadIdx.x & 63;
    if (wid >= nnodes) return;
    float hv = __half2float(h16[(size_t)wid * 64 + lane]);
#pragma unroll
    for (int k = 0; k < 4; ++k) {
        float plo = hv * att_w_l[k * 128 + lane];
        float phi = hv * att_w_l[k * 128 + 64 + lane];
#pragma unroll
        for (int off = 32; off >= 1; off >>= 1) {
            plo += __shfl_xor(plo, off);
            phi += __shfl_xor(phi, off);
        }
        if (lane == 0) {
            s[(size_t)wid * 8 + 2 * k] = plo;
            s[(size_t)wid * 8 + 2 * k + 1] = phi;
        }
    }
}

// ---------------------------------------------------------------------------
// CSR build, 4 directed graphs (slot k, node n) -> flat k*N+n.
// count_kernel: histogram + per-edge rank (atomic return).
// ---------------------------------------------------------------------------
__global__ __launch_bounds__(256) void count_kernel(const int* __restrict__ ep,
                                                    const int* __restrict__ en,
                                                    int* __restrict__ cnt,
                                                    int* __restrict__ rnk,
                                                    int N, int E) {
    int i = blockIdx.x * blockDim.x + threadIdx.x;
    if (i < E) {
        int r = ep[i], c = ep[E + i];
        rnk[i]     = atomicAdd(&cnt[0 * N + r], 1);
        rnk[E + i] = atomicAdd(&cnt[1 * N + c], 1);
    } else if (i < 2 * E) {
        int j = i - E;
        int r = en[j], c = en[E + j];
        rnk[2 * E + j] = atomicAdd(&cnt[2 * N + r], 1);
        rnk[3 * E + j] = atomicAdd(&cnt[3 * N + c], 1);
    }
}

// Exclusive scan, 3-kernel hierarchy. 256 thr x 8 elem = 2048/block.
__global__ __launch_bounds__(256) void scan1(const int* __restrict__ in,
                                             int* __restrict__ out,
                                             int* __restrict__ part, int M) {
    __shared__ int ts[256];
    int base = blockIdx.x * 2048 + threadIdx.x * 8;
    int v[8];
    int run = 0;
#pragma unroll
    for (int t = 0; t < 8; ++t) {
        int x = (base + t < M) ? in[base + t] : 0;
        v[t] = run;
        run += x;
    }
    ts[threadIdx.x] = run;
    __syncthreads();
    for (int off = 1; off < 256; off <<= 1) {
        int t = (threadIdx.x >= off) ? ts[threadIdx.x - off] : 0;
        __syncthreads();
        ts[threadIdx.x] += t;
        __syncthreads();
    }
    int texcl = ts[threadIdx.x] - run;
    if (part && threadIdx.x == 255) part[blockIdx.x] = ts[255];
#pragma unroll
    for (int t = 0; t < 8; ++t)
        if (base + t < M) out[base + t] = v[t] + texcl;
}

// add block offsets + sentinel
__global__ __launch_bounds__(256) void scan3(int* __restrict__ off,
                                             const int* __restrict__ part,
                                             int M, int total) {
    int base = blockIdx.x * 2048 + threadIdx.x * 8;
    int p = part[blockIdx.x];
#pragma unroll
    for (int t = 0; t < 8; ++t) {
        int i = base + t;
        if (i < M) off[i] += p;
    }
    if (blockIdx.x == 0 && threadIdx.x == 0) off[M] = total;
}

// ---------------------------------------------------------------------------
// XCD-pinned bucketed fill: bucket = blockIdx.x & 7 (round-robin XCD map),
// so each 3.2MB ent2 window is written by exactly one XCD's L2 ->
// full-line writebacks. ent2[pos] = {dst, src}, one 8B store per entry.
// Correctness does not depend on the XCD mapping (only locality does).
// ---------------------------------------------------------------------------
__global__ __launch_bounds__(256) void fill_bucket(const int* __restrict__ ep,
                                                   const int* __restrict__ en,
                                                   const int* __restrict__ off,
                                                   const int* __restrict__ rnk,
                                                   int2* __restrict__ ent2,
                                                   int N, int E, int bsz) {
    int bucket = blockIdx.x & 7;
    int i = (blockIdx.x >> 3) * blockDim.x + threadIdx.x;
    int lo = bucket * bsz, hi = lo + bsz;
    if (i < E) {
        int r = ep[i], c = ep[E + i];
        int p0 = off[0 * N + r] + rnk[i];
        if (p0 >= lo && p0 < hi) ent2[p0] = make_int2(c, r);
        int p1 = off[1 * N + c] + rnk[E + i];
        if (p1 >= lo && p1 < hi) ent2[p1] = make_int2(r, c);
    } else if (i < 2 * E) {
        int j = i - E;
        int r = en[j], c = en[E + j];
        int p2 = off[2 * N + r] + rnk[2 * E + j];
        if (p2 >= lo && p2 < hi) ent2[p2] = make_int2(c, r);
        int p3 = off[3 * N + c] + rnk[3 * E + j];
        if (p3 >= lo && p3 < hi) ent2[p3] = make_int2(r, c);
    }
}

// ---------------------------------------------------------------------------
// Per-entry scores: score16[j] = fp16(exp(tanh(s[own][2k] + s[ent][2k+1] + b[k])))
// ent2[j] = {dst, own}; k recovered via segment boundaries off[N],off[2N],off[3N].
// ---------------------------------------------------------------------------
__global__ __launch_bounds__(256) void score_kernel(const int2* __restrict__ ent2,
                                                    const int* __restrict__ off,
                                                    const float* __restrict__ s,
                                                    const float* __restrict__ att_b_l,
                                                    __half* __restrict__ score16,
                                                    int N, int total) {
    int j = blockIdx.x * blockDim.x + threadIdx.x;
    if (j >= total) return;
    int b1 = off[N], b2 = off[2 * N], b3 = off[3 * N];
    int k = (j >= b1) + (j >= b2) + (j >= b3);
    int2 e = ent2[j];
    float t = s[(size_t)e.y * 8 + 2 * k] + s[(size_t)e.x * 8 + 2 * k + 1] + att_b_l[k];
    score16[j] = __float2half_rn(expf(tanhf(t)));
}

// ---------------------------------------------------------------------------
// CSR aggregate: one wave per (node n, slot k). 8-way unrolled, masked tail.
//   outs16[n][64k + lane] = sum_{j in seg(k,n)} h16[ent2[j].x][lane] * score16[j]
// Pure gather + FMA (scores precomputed).
// ---------------------------------------------------------------------------
__global__ __launch_bounds__(256) void aggregate(const __half* __restrict__ h16,
                                                 const int* __restrict__ off,
                                                 const int2* __restrict__ ent2,
                                                 const __half* __restrict__ score16,
                                                 __half* __restrict__ outs16, int N) {
    int n = blockIdx.x;
    int k = threadIdx.x >> 6;
    int lane = threadIdx.x & 63;
    int beg = off[k * N + n];
    int end = off[k * N + n + 1];
    float acc = 0.f;
    for (int j = beg; j < end; j += 8) {
        int e1 = end - 1;
        int d[8];
        float hh[8], sc[8];
#pragma unroll
        for (int t = 0; t < 8; ++t) {
            int jt = min(j + t, e1);
            d[t] = ent2[jt].x;
            sc[t] = __half2float(score16[jt]);
        }
#pragma unroll
        for (int t = 0; t < 8; ++t) hh[t] = __half2float(h16[(size_t)d[t] * 64 + lane]);
#pragma unroll
        for (int t = 0; t < 8; ++t)
            acc += (t == 0 || j + t < end) ? hh[t] * sc[t] : 0.f;
    }
    outs16[(size_t)n * 256 + k * 64 + lane] = __float2half_rn(acc);
}

// ---------------------------------------------------------------------------
// Head gather: x12[b] = [zc[idx1[b]], zc[idx2[b]]], x21[b] = swapped.
// ---------------------------------------------------------------------------
__global__ __launch_bounds__(256) void gather_heads(const float* __restrict__ emb0,
                                                    const float* __restrict__ emb1,
                                                    const int* __restrict__ idx1,
                                                    const int* __restrict__ idx2,
                                                    float* __restrict__ x12,
                                                    float* __restrict__ x21, int B) {
    int b = blockIdx.x;
    int j = threadIdx.x;
    int i1 = idx1[b], i2 = idx2[b];
    int seg = j >> 6, o = j & 63;
    const float* e = (seg & 1) ? emb1 : emb0;
    int n12 = (seg < 2) ? i1 : i2;
    int n21 = (seg < 2) ? i2 : i1;
    x12[(size_t)b * 256 + j] = e[(size_t)n12 * 64 + o];
    x21[(size_t)b * 256 + j] = e[(size_t)n21 * 64 + o];
}

// ---------------------------------------------------------------------------
// Final tiny GEMM: out[nrows x 2] = Z[nrows x 64] @ W[64 x 2] + bias
// ---------------------------------------------------------------------------
__global__ __launch_bounds__(256) void gemm_m2(const float* __restrict__ Z,
                                               const float* __restrict__ W,
                                               const float* __restrict__ bias,
                                               float* __restrict__ out, int nrows) {
    int row = blockIdx.x * blockDim.x + threadIdx.x;
    if (row >= nrows) return;
    float acc0 = bias[0], acc1 = bias[1];
#pragma unroll
    for (int kk = 0; kk < 64; ++kk) {
        float v = Z[(size_t)row * 64 + kk];
        acc0 += v * W[kk * 2 + 0];
        acc1 += v * W[kk * 2 + 1];
    }
    out[(size_t)row * 2 + 0] = acc0;
    out[(size_t)row * 2 + 1] = acc1;
}

static inline int cdiv(int a, int b) { return (a + b - 1) / b; }

extern "C" void kernel_launch(void* const* d_in, const int* in_sizes, int n_in,
                              void* d_out, int out_size, void* d_ws, size_t ws_size,
                              hipStream_t stream) {
    const float* x       = (const float*)d_in[0];
    const int* edge_pos  = (const int*)d_in[1];
    const int* edge_neg  = (const int*)d_in[2];
    const int* idx1      = (const int*)d_in[3];
    const int* idx2      = (const int*)d_in[4];
    const float* lin_w0  = (const float*)d_in[5];
    const float* lin_b0  = (const float*)d_in[6];
    const float* lin_w1  = (const float*)d_in[7];
    const float* lin_b1  = (const float*)d_in[8];
    const float* att_w   = (const float*)d_in[9];   // (2,4,128)
    const float* att_b   = (const float*)d_in[10];  // (2,4)
    const float* cat_w   = (const float*)d_in[11];  // (2,256,64)
    const float* cat_b   = (const float*)d_in[12];  // (2,64)
    const float* sw1 = (const float*)d_in[13];
    const float* sb1 = (const float*)d_in[14];
    const float* sw2 = (const float*)d_in[15];
    const float* sb2 = (const float*)d_in[16];
    const float* sw3 = (const float*)d_in[17];
    const float* sb3 = (const float*)d_in[18];
    const float* sw4 = (const float*)d_in[19];
    const float* sb4 = (const float*)d_in[20];
    const float* dw1 = (const float*)d_in[21];
    const float* db1 = (const float*)d_in[22];
    const float* dw2 = (const float*)d_in[23];
    const float* db2 = (const float*)d_in[24];
    float* out = (float*)d_out;

    const int N = in_sizes[0] / 64;  // 100000
    const int E = in_sizes[1] / 2;   // 800000
    const int B = in_sizes[3];       // 4096
    const int NB = 8;                // fill buckets == XCD count

    // -------- workspace layout --------
    float* ws = (float*)d_ws;
    // Region A (N*64 f32 = 25.6MB): h16 (12.8MB) | off (1.6MB) | score16 (6.4MB)
    __half* h16 = (__half*)ws;
    int* off = (int*)(ws + (size_t)N * 32);                  // 4N+1 ints
    __half* score16 = (__half*)(ws + (size_t)N * 36 + 16);   // 4E halves
    // Region B (N*256 f32): outs16 (fp16, half the slot) + build temps
    float* outsR = ws + (size_t)N * 64;
    __half* outs16 = (__half*)outsR;
    float* sbuf = outsR + (size_t)N * 256;     // N*8 f32
    float* emb0 = sbuf + (size_t)N * 8;        // N*64 f32
    float* emb1 = emb0 + (size_t)N * 64;       // N*64 f32

    // Region E (emb1, dead until final cat-GEMM): ent2 (4E int2 = 25.6MB exact)
    int2* ent2 = (int2*)emb1;

    // build temps in region B (dead until first aggregate):
    int* cnt  = (int*)outsR;                   // 4N
    int* rnk  = cnt + (size_t)4 * N;           // 4E
    int* part = rnk + (size_t)4 * E;           // scan partials

    // heads overlay region A after GNN (watermark 10.5MB < h16's 12.8MB):
    float* x12 = ws;                     // B*256
    float* x21 = x12 + (size_t)B * 256;  // B*256
    float* hsA = x21 + (size_t)B * 256;  // B*64
    float* hsB = hsA + (size_t)B * 64;   // B*64

    const int gemm_blocks_N = cdiv(N, 64);
    const int gemm_blocks_B = cdiv(B, 64);
    const int s_blocks = cdiv(N, 4);
    const int eg_blocks = cdiv(2 * E, 256);
    const int M4 = 4 * N;
    const int scan_blocks = cdiv(M4, 2048);
    const int bsz = cdiv(4 * E, NB);
    const int sc_blocks = cdiv(4 * E, 256);

    // -------- build CSR (shared by both layers) --------
    hipMemsetAsync(cnt, 0, (size_t)M4 * sizeof(int), stream);
    count_kernel<<<eg_blocks, 256, 0, stream>>>(edge_pos, edge_neg, cnt, rnk, N, E);
    scan1<<<scan_blocks, 256, 0, stream>>>(cnt, off, part, M4);
    scan1<<<1, 256, 0, stream>>>(part, part, nullptr, scan_blocks);
    scan3<<<scan_blocks, 256, 0, stream>>>(off, part, M4, 4 * E);
    fill_bucket<<<eg_blocks * NB, 256, 0, stream>>>(edge_pos, edge_neg, off,
                                                    rnk, ent2, N, E, bsz);

    // -------- GNN layers --------
    for (int l = 0; l < 2; ++l) {
        const void* zin = (l == 0) ? (const void*)x : (const void*)emb0;
        const float* lw = (l == 0) ? lin_w0 : lin_w1;
        const float* lb = (l == 0) ? lin_b0 : lin_b1;
        gemm64<0, true, false><<<gemm_blocks_N, 256, 0, stream>>>(zin, lw, lb, h16, N, 64);
        s_kernel<<<s_blocks, 256, 0, stream>>>(h16, att_w + (size_t)l * 512, sbuf, N);
        score_kernel<<<sc_blocks, 256, 0, stream>>>(ent2, off, sbuf,
                                                    att_b + (size_t)l * 4, score16,
                                                    N, 4 * E);
        aggregate<<<N, 256, 0, stream>>>(h16, off, ent2, score16, outs16, N);
        float* embl = (l == 0) ? emb0 : emb1;
        gemm64<2, false, true><<<gemm_blocks_N, 256, 0, stream>>>(outs16,
                                                                  cat_w + (size_t)l * 16384,
                                                                  cat_b + (size_t)l * 64,
                                                                  embl, N, 256);
    }

    // -------- heads --------
    gather_heads<<<B, 256, 0, stream>>>(emb0, emb1, idx1, idx2, x12, x21, B);

    gemm64<1, false, false><<<gemm_blocks_B, 256, 0, stream>>>(x12, sw1, sb1, hsA, B, 256);
    gemm64<1, false, false><<<gemm_blocks_B, 256, 0, stream>>>(hsA, sw2, sb2, hsB, B, 64);
    gemm64<1, false, false><<<gemm_blocks_B, 256, 0, stream>>>(hsB, sw3, sb3, hsA, B, 64);
    gemm_m2<<<cdiv(B, 256), 256, 0, stream>>>(hsA, sw4, sb4, out, B);

    gemm64<1, false, false><<<gemm_blocks_B, 256, 0, stream>>>(x12, dw1, db1, hsB, B, 256);
    gemm_m2<<<cdiv(B, 256), 256, 0, stream>>>(hsB, dw2, db2, out + (size_t)B * 2, B);
    gemm64<1, false, false><<<gemm_blocks_B, 256, 0, stream>>>(x21, dw1, db1, hsB, B, 256);
    gemm_m2<<<cdiv(B, 256), 256, 0, stream>>>(hsB, dw2, db2, out + (size_t)B * 4, B);
}